// Round 10
// baseline (383.245 us; speedup 1.0000x reference)
//
#include <hip/hip_runtime.h>
#include <hip/hip_bf16.h>
#include <math.h>

// B=32, S=1024, D=1024, H=16, dh=64, T=8, E=8, HID=4096
// Outputs fp32 concat: final(262144), moe_loss(1), attn_weights(262144)

using bf16x8  = __attribute__((ext_vector_type(8))) short;
using f32x4   = __attribute__((ext_vector_type(4))) float;
using short4v = __attribute__((ext_vector_type(4))) short;

__device__ inline short f2bf(float f) {
  unsigned u = __builtin_bit_cast(unsigned, f);
  u = (u + 0x7fffu + ((u >> 16) & 1u)) >> 16;
  return (short)u;
}
// 16B-unit XOR swizzle within a 64B (32-short) k-row segment; k in [0,32)
__device__ inline int bswz(int k, int n) {
  return (((k >> 3) ^ ((n >> 2) & 3)) << 3) | (k & 7);
}

#define LGKM0() asm volatile("s_waitcnt lgkmcnt(0)" ::: "memory")
#define RAWBAR() do { __builtin_amdgcn_s_barrier(); __builtin_amdgcn_sched_barrier(0); } while (0)

// ---------------- workspace layout (float offsets) ----------------
static constexpr long OFF_Q       = 0;         // 8192
static constexpr long OFF_QWB     = 8192;      // 65536 f = 131072 bf16
static constexpr long OFF_QB      = 73728;     // 128
static constexpr long OFF_PSUM    = 73856;     // 8
static constexpr long OFF_FCNT    = 73864;     // 8
static constexpr long OFF_GATES   = 73872;     // 2048
static constexpr long OFF_CTX     = 75920;     // 262144 fp32
static constexpr long OFF_ATTNOUT = 338064;    // 262144 fp32
static constexpr long OFF_EO      = 600208;    // 2097152 fp32 [e][n][d] (zeroed)
static constexpr long OFF_CTXP    = 2697360;   // 1048576 fp32 (4 partials)
static constexpr long OFF_AOP     = 3745936;   // 1048576 fp32 (4 partials)
static constexpr long OFF_SCORES  = 4794512;   // 4194304 fp32 [b][ht][s]
static constexpr long OFF_AXP     = 8988816;   // 16777216 fp32: 4 planes [kc][h][b][t][d]
static constexpr long OFF_YB      = 25766032;  // 131072 f = 262144 bf16
static constexpr long OFF_HB      = 25897104;  // 4194304 f = 8388608 bf16 [e][n][hid]
// end 30091408 floats ~ 120 MB

// ---------------- q: one wave per output element ----------------
__global__ __launch_bounds__(256) void compute_q_k(const float* __restrict__ probe,
                                                   const float* __restrict__ in_w,
                                                   const float* __restrict__ in_b,
                                                   float* __restrict__ q) {
  int wid = threadIdx.x >> 6, lane = threadIdx.x & 63;
  int idx = blockIdx.x * 4 + wid;   // t*1024 + d
  int t = idx >> 10, d = idx & 1023;
  const float* pr = probe + (long)t * 1024;
  const float* wr = in_w + (long)d * 1024;
  float s = 0.f;
  for (int k = lane * 4; k < 1024; k += 256) {
    float4 a = *(const float4*)&pr[k];
    float4 b = *(const float4*)&wr[k];
    s += a.x * b.x + a.y * b.y + a.z * b.z + a.w * b.w;
  }
  for (int o = 32; o; o >>= 1) s += __shfl_xor(s, o);
  if (!lane) q[idx] = s + in_b[d];
}

// ---------------- qwb[h*8+t][d] (bf16); qb[ht] ----------------
__global__ __launch_bounds__(256) void compute_qw_k(const float* __restrict__ q,
                                                    const float* __restrict__ in_w,
                                                    const float* __restrict__ in_b,
                                                    short* __restrict__ qwb,
                                                    float* __restrict__ qb) {
  const int h = blockIdx.y;
  const int tid = threadIdx.x;
  const int d = blockIdx.x * 256 + tid;
  __shared__ float qh[8][64];
  if (tid < 64) {
#pragma unroll
    for (int t = 0; t < 8; ++t) qh[t][tid] = q[t * 1024 + h * 64 + tid] * 0.125f;
  }
  __syncthreads();
  const float* wk = in_w + 1048576 + (long)h * 64 * 1024;
  float acc[8];
#pragma unroll
  for (int t = 0; t < 8; ++t) acc[t] = 0.f;
  for (int j = 0; j < 64; ++j) {
    float w = wk[(long)j * 1024 + d];
#pragma unroll
    for (int t = 0; t < 8; ++t) acc[t] += qh[t][j] * w;
  }
#pragma unroll
  for (int t = 0; t < 8; ++t) qwb[(long)(h * 8 + t) * 1024 + d] = f2bf(acc[t]);
  if (blockIdx.x == 0 && tid < 8) {
    float s = 0.f;
    for (int j = 0; j < 64; ++j) s += qh[tid][j] * in_b[1024 + h * 64 + j];
    qb[h * 8 + tid] = s;
  }
}

// ---------------- scores: per-b, C[ht][s] = qwb @ x[b]^T (counted-vmcnt schedule) ----------------
__global__ __launch_bounds__(512)
void gemm_sc(const short* __restrict__ qwb, const float* __restrict__ xp,
             float* __restrict__ scores) {
  const int b = blockIdx.z;
  const int n0 = blockIdx.x * 64;
  const float* B = xp + (long)b * 1048576;
  float* C = scores + (long)b * 131072;
  const int tid = threadIdx.x;
  __shared__ short As[128][40], Bs[64][40];

  f32x4 acc[2][2];
#pragma unroll
  for (int i = 0; i < 2; ++i)
#pragma unroll
    for (int j = 0; j < 2; ++j)
#pragma unroll
      for (int qq = 0; qq < 4; ++qq) acc[i][j][qq] = 0.f;

  const int wid = tid >> 6, lane = tid & 63;
  const int wm = wid & 3, wn = wid >> 2;
  const int r = lane & 15, kg = (lane >> 4) * 8;
  const int am = tid >> 2, ak8 = (tid & 3) * 8;
  const int bn = tid >> 3, bk4 = (tid & 7) * 4;

  bf16x8 ra;
  float4 rb;
  auto loadT = [&](int k0) {
    ra = *(const bf16x8*)&qwb[(long)am * 1024 + k0 + ak8];
    rb = *(const float4*)&B[(long)(n0 + bn) * 1024 + k0 + bk4];
  };
  auto storeT = [&]() {
    *(bf16x8*)&As[am][ak8] = ra;
    short4v s;
    s.x = f2bf(rb.x); s.y = f2bf(rb.y); s.z = f2bf(rb.z); s.w = f2bf(rb.w);
    *(short4v*)&Bs[bn][bk4] = s;
  };
  auto compute = [&]() {
    bf16x8 af[2], bf_[2];
#pragma unroll
    for (int i = 0; i < 2; ++i) af[i] = *(const bf16x8*)&As[wm * 32 + i * 16 + r][kg];
#pragma unroll
    for (int j = 0; j < 2; ++j) bf_[j] = *(const bf16x8*)&Bs[wn * 32 + j * 16 + r][kg];
#pragma unroll
    for (int i = 0; i < 2; ++i)
#pragma unroll
      for (int j = 0; j < 2; ++j)
        acc[i][j] = __builtin_amdgcn_mfma_f32_16x16x32_bf16(af[i], bf_[j], acc[i][j], 0, 0, 0);
  };

  constexpr int NTILES = 32;
  loadT(0);
  storeT();
  loadT(32);
  LGKM0(); RAWBAR();
  for (int t = 0; t < NTILES; ++t) {
    compute();
    if (t + 1 < NTILES) {
      LGKM0(); RAWBAR();           // all waves done reading
      storeT();                    // tile t+1 (counted vmcnt wait)
      if (t + 2 < NTILES) loadT((t + 2) * 32);
      LGKM0(); RAWBAR();           // writes visible; t+2 loads stay in flight
    }
  }

  const int q4 = (lane >> 4) * 4;
#pragma unroll
  for (int i = 0; i < 2; ++i)
#pragma unroll
    for (int j = 0; j < 2; ++j) {
      int gn = n0 + wn * 32 + j * 16 + r;
#pragma unroll
      for (int qq = 0; qq < 4; ++qq) {
        int m = wm * 32 + i * 16 + q4 + qq;
        C[(long)m * 1024 + gn] = acc[i][j][qq];
      }
    }
}

// ---------------- split-bf16 MFMA GEMM (fp32-grade), counted-vmcnt schedule ----------------
// A: M x K fp32 (lda); APL partial planes summed (stride zA2); AKB adds kbias[k].
// B: BTRANS ? K x N row-major (swizzle-staged) : N x K row-major.
// z -> (zo=z/KS, kc=z%KS). EPI: 0 plain fp32; 4 ax scatter [h][bt][d]
template<int WM, int WN, int KS, bool AKB, bool BTRANS, int APL, int EPI>
__global__ __launch_bounds__(WM * WN * 64)
void gemm_ss(const float* __restrict__ Ap, const float* __restrict__ Bp,
             const float* __restrict__ kbias, float* __restrict__ Cp,
             int lda, int ldb, int K,
             long zA, long zA2, long zB, long zC, long ZKC, int ldc) {
  constexpr int BM = WM * 64, BN = WN * 64, BK = 32, NT = WM * WN * 64, PK = 40;
  constexpr int LA = BM * BK / (NT * 4), LB = BN * BK / (NT * 4);
  constexpr int F4 = BN / 4;
  const int z = blockIdx.z, zo = z / KS, kc = z % KS;
  const float* A = Ap + zA * zo + (long)kc * K;
  const float* B = BTRANS ? (Bp + zB * zo + (long)kc * K * ldb)
                          : (Bp + zB * zo + (long)kc * K);
  const float* kb = kbias + (long)kc * K;
  float* C = Cp + zC * zo + ZKC * kc;
  const int tid = threadIdx.x;
  const int m0 = blockIdx.y * BM, n0 = blockIdx.x * BN;
  __shared__ short Ah[BM][PK], Al[BM][PK], Bh[BN][PK], Bl[BN][PK];

  f32x4 acc[4][4];
#pragma unroll
  for (int i = 0; i < 4; ++i)
#pragma unroll
    for (int j = 0; j < 4; ++j)
#pragma unroll
      for (int qq = 0; qq < 4; ++qq) acc[i][j][qq] = 0.f;

  const int wid = tid >> 6, lane = tid & 63;
  const int wm = wid % WM, wn = wid / WM;
  const int r = lane & 15, kg = (lane >> 4) * 8;

  float4 ra[LA], rb[LB];

  auto loadT = [&](int k0) {
#pragma unroll
    for (int i = 0; i < LA; ++i) {
      int f = tid + i * NT;
      int m = f >> 3, k4 = (f & 7) * 4;
      long ofs = (long)(m0 + m) * lda + k0 + k4;
      ra[i] = *(const float4*)&A[ofs];
#pragma unroll
      for (int p = 1; p < APL; ++p) {
        float4 v2 = *(const float4*)&A[ofs + zA2 * p];
        ra[i].x += v2.x; ra[i].y += v2.y; ra[i].z += v2.z; ra[i].w += v2.w;
      }
      if (AKB) {
        float4 kv = *(const float4*)&kb[k0 + k4];
        ra[i].x += kv.x; ra[i].y += kv.y; ra[i].z += kv.z; ra[i].w += kv.w;
      }
    }
#pragma unroll
    for (int i = 0; i < LB; ++i) {
      int f = tid + i * NT;
      if (BTRANS) {
        int k = f / F4, n4 = (f % F4) * 4;
        rb[i] = *(const float4*)&B[(long)(k0 + k) * ldb + n0 + n4];
      } else {
        int n = f >> 3, k4 = (f & 7) * 4;
        rb[i] = *(const float4*)&B[(long)(n0 + n) * ldb + k0 + k4];
      }
    }
  };

  auto storeT = [&]() {
#pragma unroll
    for (int i = 0; i < LA; ++i) {
      int f = tid + i * NT;
      int m = f >> 3, k4 = (f & 7) * 4;
      short4v h, l;
      float vv[4] = {ra[i].x, ra[i].y, ra[i].z, ra[i].w};
#pragma unroll
      for (int j = 0; j < 4; ++j) {
        unsigned u = __builtin_bit_cast(unsigned, vv[j]);
        h[j] = (short)(u >> 16);
        l[j] = f2bf(vv[j] - __builtin_bit_cast(float, u & 0xFFFF0000u));
      }
      *(short4v*)&Ah[m][k4] = h;
      *(short4v*)&Al[m][k4] = l;
    }
#pragma unroll
    for (int i = 0; i < LB; ++i) {
      int f = tid + i * NT;
      float vv[4] = {rb[i].x, rb[i].y, rb[i].z, rb[i].w};
      if (BTRANS) {
        int k = f / F4, n4 = (f % F4) * 4;
        int col = bswz(k, n4);
#pragma unroll
        for (int j = 0; j < 4; ++j) {
          unsigned u = __builtin_bit_cast(unsigned, vv[j]);
          Bh[n4 + j][col] = (short)(u >> 16);
          Bl[n4 + j][col] = f2bf(vv[j] - __builtin_bit_cast(float, u & 0xFFFF0000u));
        }
      } else {
        int n = f >> 3, k4 = (f & 7) * 4;
        short4v h, l;
#pragma unroll
        for (int j = 0; j < 4; ++j) {
          unsigned u = __builtin_bit_cast(unsigned, vv[j]);
          h[j] = (short)(u >> 16);
          l[j] = f2bf(vv[j] - __builtin_bit_cast(float, u & 0xFFFF0000u));
        }
        *(short4v*)&Bh[n][k4] = h;
        *(short4v*)&Bl[n][k4] = l;
      }
    }
  };

  auto compute = [&]() {
    bf16x8 ah[4], al[4], bh[4], bl[4];
#pragma unroll
    for (int i = 0; i < 4; ++i) {
      ah[i] = *(const bf16x8*)&Ah[wm * 64 + i * 16 + r][kg];
      al[i] = *(const bf16x8*)&Al[wm * 64 + i * 16 + r][kg];
    }
#pragma unroll
    for (int j = 0; j < 4; ++j) {
      int brow = wn * 64 + j * 16 + r;
      int bcol = BTRANS ? bswz(kg, brow) : kg;
      bh[j] = *(const bf16x8*)&Bh[brow][bcol];
      bl[j] = *(const bf16x8*)&Bl[brow][bcol];
    }
#pragma unroll
    for (int i = 0; i < 4; ++i)
#pragma unroll
      for (int j = 0; j < 4; ++j) {
        acc[i][j] = __builtin_amdgcn_mfma_f32_16x16x32_bf16(ah[i], bh[j], acc[i][j], 0, 0, 0);
        acc[i][j] = __builtin_amdgcn_mfma_f32_16x16x32_bf16(ah[i], bl[j], acc[i][j], 0, 0, 0);
        acc[i][j] = __builtin_amdgcn_mfma_f32_16x16x32_bf16(al[i], bh[j], acc[i][j], 0, 0, 0);
      }
  };

  const int NTILES = K / BK;
  loadT(0);
  storeT();
  if (NTILES > 1) loadT(BK);
  LGKM0(); RAWBAR();
  for (int t = 0; t < NTILES; ++t) {
    compute();
    if (t + 1 < NTILES) {
      LGKM0(); RAWBAR();
      storeT();
      if (t + 2 < NTILES) loadT((t + 2) * BK);
      LGKM0(); RAWBAR();
    }
  }

  const int q4 = (lane >> 4) * 4;
#pragma unroll
  for (int i = 0; i < 4; ++i) {
    int gmb = m0 + wm * 64 + i * 16 + q4;
#pragma unroll
    for (int j = 0; j < 4; ++j) {
      int gn = n0 + wn * 64 + j * 16 + r;
#pragma unroll
      for (int qq = 0; qq < 4; ++qq) {
        float v = acc[i][j][qq];
        int m = gmb + qq;
        if constexpr (EPI == 0) {
          C[(long)m * ldc + gn] = v;
        } else {  // EPI == 4: m = h*8+t ; write [h][b-t-row][d]
          C[(long)(m >> 3) * 262144 + (long)(m & 7) * 1024 + gn] = v;
        }
      }
    }
  }
}

// ---------------- MoE MFMA GEMM: A bf16 MxK, B fp32 KxN (swizzled), LDS dbuf + counted vmcnt ----------------
// EPI: 2 gelu->bf16 +bias[n]; 5 atomicAdd fp32 (no bias)
template<int WM, int WN, int KS, int EPI>
__global__ __launch_bounds__(WM * WN * 64)
void gemm_bw(const short* __restrict__ Ap, const float* __restrict__ Bp,
             const float* __restrict__ biasp, void* __restrict__ Cp,
             int lda, int ldb, int K, long zA, long zB, long zBias, long zC, int ldc) {
  constexpr int BM = WM * 64, BN = WN * 64, BK = 32, NT = WM * WN * 64, PK = 40;
  constexpr int LA = BM * BK / (NT * 8), LB = BN * BK / (NT * 4);
  constexpr int F4 = BN / 4;
  const int z = blockIdx.z, zo = z / KS, kc = z % KS;
  const short* A = Ap + zA * zo + (long)kc * K;
  const float* B = Bp + zB * zo + (long)kc * K * ldb;
  const float* bias = biasp + zBias * zo;
  const int tid = threadIdx.x;
  const int m0 = blockIdx.y * BM, n0 = blockIdx.x * BN;
  __shared__ short As[2][BM][PK], Bs[2][BN][PK];

  f32x4 acc[4][4];
#pragma unroll
  for (int i = 0; i < 4; ++i)
#pragma unroll
    for (int j = 0; j < 4; ++j)
#pragma unroll
      for (int qq = 0; qq < 4; ++qq) acc[i][j][qq] = 0.f;

  const int wid = tid >> 6, lane = tid & 63;
  const int wm = wid % WM, wn = wid / WM;
  const int r = lane & 15, kg = (lane >> 4) * 8;

  bf16x8 ra[LA];
  float4 rb[LB];

  auto loadT = [&](int k0) {
#pragma unroll
    for (int i = 0; i < LA; ++i) {
      int f = tid + i * NT;
      int m = f >> 2, k8 = (f & 3) * 8;
      ra[i] = *(const bf16x8*)&A[(long)(m0 + m) * lda + k0 + k8];
    }
#pragma unroll
    for (int i = 0; i < LB; ++i) {
      int f = tid + i * NT;
      int k = f / F4, n4 = (f % F4) * 4;
      rb[i] = *(const float4*)&B[(long)(k0 + k) * ldb + n0 + n4];
    }
  };

  auto storeT = [&](int bi) {
#pragma unroll
    for (int i = 0; i < LA; ++i) {
      int f = tid + i * NT;
      int m = f >> 2, k8 = (f & 3) * 8;
      *(bf16x8*)&As[bi][m][k8] = ra[i];
    }
#pragma unroll
    for (int i = 0; i < LB; ++i) {
      int f = tid + i * NT;
      int k = f / F4, n4 = (f % F4) * 4;
      int col = bswz(k, n4);
      Bs[bi][n4 + 0][col] = f2bf(rb[i].x);
      Bs[bi][n4 + 1][col] = f2bf(rb[i].y);
      Bs[bi][n4 + 2][col] = f2bf(rb[i].z);
      Bs[bi][n4 + 3][col] = f2bf(rb[i].w);
    }
  };

  auto compute = [&](int bi) {
    bf16x8 af[4], bfr[4];
#pragma unroll
    for (int i = 0; i < 4; ++i) af[i] = *(const bf16x8*)&As[bi][wm * 64 + i * 16 + r][kg];
#pragma unroll
    for (int j = 0; j < 4; ++j) {
      int brow = wn * 64 + j * 16 + r;
      bfr[j] = *(const bf16x8*)&Bs[bi][brow][bswz(kg, brow)];
    }
#pragma unroll
    for (int i = 0; i < 4; ++i)
#pragma unroll
      for (int j = 0; j < 4; ++j)
        acc[i][j] = __builtin_amdgcn_mfma_f32_16x16x32_bf16(af[i], bfr[j], acc[i][j], 0, 0, 0);
  };

  const int NTILES = K / BK;
  loadT(0);
  storeT(0);
  if (NTILES > 1) loadT(BK);
  LGKM0(); RAWBAR();
  for (int t = 0; t < NTILES; ++t) {
    compute(t & 1);
    if (t + 1 < NTILES) {
      storeT((t + 1) & 1);               // counted vmcnt wait for tile t+1 regs
      if (t + 2 < NTILES) loadT((t + 2) * BK);  // stays in flight across barrier
      LGKM0(); RAWBAR();
    }
  }

  const int q4 = (lane >> 4) * 4;
#pragma unroll
  for (int i = 0; i < 4; ++i) {
    int gmb = m0 + wm * 64 + i * 16 + q4;
#pragma unroll
    for (int j = 0; j < 4; ++j) {
      int gn = n0 + wn * 64 + j * 16 + r;
#pragma unroll
      for (int qq = 0; qq < 4; ++qq) {
        float v = acc[i][j][qq];
        int m = gmb + qq;
        if constexpr (EPI == 2) {
          float u = v + bias[gn];
          u = 0.5f * u * (1.0f + erff(u * 0.70710678118654752f));
          ((short*)Cp + zC * zo)[(long)m * ldc + gn] = f2bf(u);
        } else {  // EPI == 5
          atomicAdd(&((float*)Cp + zC * zo)[(long)m * ldc + gn], v);
        }
      }
    }
  }
}

// ---------------- reduce 4 partials ----------------
__global__ __launch_bounds__(256) void reduce4_k(const float* __restrict__ p,
                                                 float* __restrict__ out) {
  int i = (blockIdx.x * 256 + threadIdx.x) * 4;
  float4 a = *(const float4*)&p[i];
  float4 b = *(const float4*)&p[i + 262144];
  float4 c = *(const float4*)&p[i + 524288];
  float4 d = *(const float4*)&p[i + 786432];
  float4 o;
  o.x = a.x + b.x + c.x + d.x;
  o.y = a.y + b.y + c.y + d.y;
  o.z = a.z + b.z + c.z + d.z;
  o.w = a.w + b.w + c.w + d.w;
  *(float4*)&out[i] = o;
}

// ---------------- softmax over s (in place) + qb bias ----------------
__global__ __launch_bounds__(256) void softmax_k(float* __restrict__ scores,
                                                 const float* __restrict__ qb) {
  long row = blockIdx.x;            // b*128 + ht
  float bias = qb[(int)(row & 127)];
  float* p = scores + row * 1024;
  int tid = threadIdx.x;
  int wid = tid >> 6, lane = tid & 63;
  float v[4];
  float mx = -1e30f;
#pragma unroll
  for (int i = 0; i < 4; ++i) {
    v[i] = p[tid + i * 256] + bias;
    mx = fmaxf(mx, v[i]);
  }
  for (int o = 32; o; o >>= 1) mx = fmaxf(mx, __shfl_xor(mx, o));
  __shared__ float sm[4];
  __shared__ float ss[4];
  if (!lane) sm[wid] = mx;
  __syncthreads();
  mx = fmaxf(fmaxf(sm[0], sm[1]), fmaxf(sm[2], sm[3]));
  float s = 0.f;
#pragma unroll
  for (int i = 0; i < 4; ++i) { v[i] = expf(v[i] - mx); s += v[i]; }
  for (int o = 32; o; o >>= 1) s += __shfl_xor(s, o);
  if (!lane) ss[wid] = s;
  __syncthreads();
  s = ss[0] + ss[1] + ss[2] + ss[3];
  float inv = 1.0f / s;
#pragma unroll
  for (int i = 0; i < 4; ++i) p[tid + i * 256] = v[i] * inv;
}

// ---------------- attn_weights[b][t][s] = mean_h attn ----------------
__global__ __launch_bounds__(256) void attnw_k(const float* __restrict__ attn,
                                               float* __restrict__ outw) {
  int idx = blockIdx.x * 256 + threadIdx.x;
  int b = idx >> 13;
  int r = idx & 8191;
  int t = r >> 10, s = r & 1023;
  const float* p = attn + (long)b * 131072 + (long)t * 1024 + s;
  float acc = 0.f;
#pragma unroll
  for (int h = 0; h < 16; ++h) acc += p[(long)h * 8192];
  outw[idx] = acc * (1.0f / 16.0f);
}

// ---------------- fused aop-reduce + layernorm + gate softmax + top2 ----------------
__global__ __launch_bounds__(256) void ln_gate_k(const float* __restrict__ aop,
                                                 const float* __restrict__ out_b,
                                                 const float* __restrict__ gamma,
                                                 const float* __restrict__ beta,
                                                 const float* __restrict__ gate_w,
                                                 float* __restrict__ attn_out,
                                                 short* __restrict__ yb,
                                                 float* __restrict__ gates,
                                                 float* __restrict__ Psum,
                                                 float* __restrict__ fcnt) {
  int row = blockIdx.x;        // n = b*8 + t
  int t = row & 7;
  int tid = threadIdx.x;
  int wid = tid >> 6, lane = tid & 63;
  const float* xr = aop + (long)row * 1024;
  float vals[4];
  float s = 0.f, sq = 0.f;
#pragma unroll
  for (int i = 0; i < 4; ++i) {
    int d = tid + i * 256;
    float v = xr[d] + xr[d + 262144] + xr[d + 524288] + xr[d + 786432] + out_b[d];
    attn_out[(long)row * 1024 + d] = v;
    vals[i] = v;
    s += v;
    sq += v * v;
  }
  for (int o = 32; o; o >>= 1) { s += __shfl_xor(s, o); sq += __shfl_xor(sq, o); }
  __shared__ float rs[4], rss[4];
  if (!lane) { rs[wid] = s; rss[wid] = sq; }
  __syncthreads();
  s = rs[0] + rs[1] + rs[2] + rs[3];
  sq = rss[0] + rss[1] + rss[2] + rss[3];
  float mu = s * (1.0f / 1024.0f);
  float var = sq * (1.0f / 1024.0f) - mu * mu;
  float rstd = rsqrtf(var + 1e-5f);
  __shared__ float yrow[1024];
#pragma unroll
  for (int i = 0; i < 4; ++i) {
    int d = tid + i * 256;
    float yv = (vals[i] - mu) * rstd * gamma[d] + beta[d];
    yb[(long)row * 1024 + d] = f2bf(yv);
    yrow[d] = yv;
  }
  __syncthreads();
  int e = tid & 7;
  int g = tid >> 3;
  float acc = 0.f;
  const float* gw = gate_w + (long)t * 8192;
  for (int d = g; d < 1024; d += 32) acc += yrow[d] * gw[d * 8 + e];
  __shared__ float part[256];
  __shared__ float lsh[8];
  part[tid] = acc;
  __syncthreads();
  if (tid < 8) {
    float l = 0.f;
    for (int gg = 0; gg < 32; ++gg) l += part[gg * 8 + tid];
    lsh[tid] = l;
  }
  __syncthreads();
  if (tid == 0) {
    float p[8];
    float mx = -1e30f;
    for (int k = 0; k < 8; ++k) mx = fmaxf(mx, lsh[k]);
    float sum = 0.f;
    for (int k = 0; k < 8; ++k) { p[k] = expf(lsh[k] - mx); sum += p[k]; }
    float inv = 1.0f / sum;
    for (int k = 0; k < 8; ++k) p[k] *= inv;
    int i0 = 0;
    for (int k = 1; k < 8; ++k) if (p[k] > p[i0]) i0 = k;
    int i1 = -1;
    for (int k = 0; k < 8; ++k) if (k != i0 && (i1 < 0 || p[k] > p[i1])) i1 = k;
    float tot = p[i0] + p[i1];
    for (int k = 0; k < 8; ++k)
      gates[(long)row * 8 + k] = (k == i0) ? p[i0] / tot : (k == i1) ? p[i1] / tot : 0.f;
    for (int k = 0; k < 8; ++k) atomicAdd(&Psum[k], p[k]);
    atomicAdd(&fcnt[i0], 1.0f);
    atomicAdd(&fcnt[i1], 1.0f);
  }
}

// ---------------- final = attn_out(+out_b) + sum_e g_e * (eo[e] + b2[e]) ----------------
__global__ __launch_bounds__(256) void combine_k(const float* __restrict__ attn_out,
                                                 const float* __restrict__ eo,
                                                 const float* __restrict__ b2,
                                                 const float* __restrict__ gates,
                                                 float* __restrict__ outp) {
  int idx = blockIdx.x * 256 + threadIdx.x;
  int n = idx >> 10, d = idx & 1023;
  float v = attn_out[idx];
  const float* g = gates + (long)n * 8;
#pragma unroll
  for (int e = 0; e < 8; ++e) {
    float ge = g[e];
    if (ge != 0.f) v += ge * (eo[(long)e * 262144 + idx] + b2[e * 1024 + d]);
  }
  outp[idx] = v;
}

__global__ void loss_k(const float* __restrict__ Psum, const float* __restrict__ fcnt,
                       float* __restrict__ out) {
  if (threadIdx.x == 0) {
    float l = 0.f;
    for (int e = 0; e < 8; ++e) l += (fcnt[e] * (1.0f / 256.0f)) * (Psum[e] * (1.0f / 256.0f));
    out[0] = 8.0f * l;
  }
}

extern "C" void kernel_launch(void* const* d_in, const int* in_sizes, int n_in,
                              void* d_out, int out_size, void* d_ws, size_t ws_size,
                              hipStream_t stream) {
  const float* x      = (const float*)d_in[0];
  const float* probe  = (const float*)d_in[1];
  const float* in_w   = (const float*)d_in[2];
  const float* in_b   = (const float*)d_in[3];
  const float* out_w  = (const float*)d_in[4];
  const float* out_b  = (const float*)d_in[5];
  const float* gamma  = (const float*)d_in[6];
  const float* beta   = (const float*)d_in[7];
  const float* gate_w = (const float*)d_in[8];
  const float* w1     = (const float*)d_in[9];
  const float* b1     = (const float*)d_in[10];
  const float* w2     = (const float*)d_in[11];
  const float* b2     = (const float*)d_in[12];

  float* ws = (float*)d_ws;
  float* q        = ws + OFF_Q;
  short* qwb      = (short*)(ws + OFF_QWB);
  float* qb       = ws + OFF_QB;
  float* Psum     = ws + OFF_PSUM;
  float* fcnt     = ws + OFF_FCNT;
  float* gates    = ws + OFF_GATES;
  float* ctx      = ws + OFF_CTX;
  float* attn_out = ws + OFF_ATTNOUT;
  float* eo       = ws + OFF_EO;
  float* ctxp     = ws + OFF_CTXP;
  float* aop      = ws + OFF_AOP;
  float* scores   = ws + OFF_SCORES;
  float* axp      = ws + OFF_AXP;
  short* yb       = (short*)(ws + OFF_YB);
  short* hb       = (short*)(ws + OFF_HB);

  float* out_final = (float*)d_out;
  float* out_loss  = out_final + 262144;
  float* out_attnw = out_loss + 1;

  hipMemsetAsync(ws + OFF_PSUM, 0, 16 * sizeof(float), stream);
  hipMemsetAsync(eo, 0, 2097152 * sizeof(float), stream);

  compute_q_k<<<2048, 256, 0, stream>>>(probe, in_w, in_b, q);
  compute_qw_k<<<dim3(4, 16, 1), 256, 0, stream>>>(q, in_w, in_b, qwb, qb);

  // scores[b][ht][s] = qwb @ x[b]^T  (per b: M=128, N=1024, K=1024)
  gemm_sc<<<dim3(16, 1, 32), 512, 0, stream>>>(qwb, x, scores);

  softmax_k<<<4096, 256, 0, stream>>>(scores, qb);
  attnw_k<<<1024, 256, 0, stream>>>(scores, out_attnw);

  // ax partials: [kc][h][b][t][d] = attn[b](:,kc*256+:) @ x[b](kc*256+:, :)
  // (per (b,kc): M=128, N=1024, K=256), KS=4 -> 1024 blocks (4/CU)
  gemm_ss<2, 2, 4, false, true, 1, 4><<<dim3(8, 1, 128), 256, 0, stream>>>(
      scores, x, qb /*unused*/, axp, 1024, 1024, 256,
      131072L, 0L, 1048576L, 8192L, 4194304L, 1024);

  // ctx partials: per (h, kc): M=256, N=64, K=256 split; A = sum of 4 axp planes
  gemm_ss<1, 1, 4, false, false, 4, 0><<<dim3(1, 4, 64), 64, 0, stream>>>(
      axp, in_w + 2097152, qb /*unused*/, ctxp, 1024, 1024, 256,
      262144L, 4194304L, 65536L, 64L, 262144L, 1024);
  reduce4_k<<<256, 256, 0, stream>>>(ctxp, ctx);

  // attn_out partials: A = ctx + bv(kbias), B = out_w  (M=256, N=1024, K=256 x4) split
  gemm_ss<1, 1, 4, true, false, 1, 0><<<dim3(16, 4, 4), 64, 0, stream>>>(
      ctx, out_w, in_b + 2048, aop, 1024, 1024, 256,
      0L, 0L, 0L, 0L, 262144L, 1024);

  // fused reduce + layernorm + gate + top2 (writes attn_out with out_b folded)
  ln_gate_k<<<256, 256, 0, stream>>>(aop, out_b, gamma, beta, gate_w, attn_out,
                                     yb, gates, Psum, fcnt);

  // h[e] = gelu(yb @ w1[e] + b1[e])  (M=256, N=4096, K=1024), 128-thr, 1024 blocks
  gemm_bw<2, 1, 1, 2><<<dim3(64, 2, 8), 128, 0, stream>>>(
      yb, w1, b1, hb, 1024, 4096, 1024, 0L, 4194304L, 4096L, 1048576L, 4096);

  // eo[e] += hb @ w2[e]  (M=256, N=1024, K=1024 x4 ksplit, atomic), 128-thr, 1024 blocks
  gemm_bw<2, 1, 4, 5><<<dim3(16, 2, 32), 128, 0, stream>>>(
      hb, w2, b2 /*unused*/, eo, 4096, 1024, 1024, 1048576L, 4194304L, 0L, 262144L, 1024);

  combine_k<<<1024, 256, 0, stream>>>(attn_out, eo, b2, gates, out_final);
  loss_k<<<1, 64, 0, stream>>>(Psum, fcnt, out_loss);
}

// Round 11
// 352.829 us; speedup vs baseline: 1.0862x; 1.0862x over previous
//
#include <hip/hip_runtime.h>
#include <hip/hip_bf16.h>
#include <math.h>

// B=32, S=1024, D=1024, H=16, dh=64, T=8, E=8, HID=4096
// Outputs fp32 concat: final(262144), moe_loss(1), attn_weights(262144)

using bf16x8  = __attribute__((ext_vector_type(8))) short;
using f32x4   = __attribute__((ext_vector_type(4))) float;
using short4v = __attribute__((ext_vector_type(4))) short;

__device__ inline short f2bf(float f) {
  unsigned u = __builtin_bit_cast(unsigned, f);
  u = (u + 0x7fffu + ((u >> 16) & 1u)) >> 16;
  return (short)u;
}
// 16B-unit XOR swizzle; k in [0,64) (works for BK<=64, rows padded to >=k+8)
__device__ inline int bswz(int k, int n) {
  return (((k >> 3) ^ ((n >> 2) & 3)) << 3) | (k & 7);
}

#define LGKM0() asm volatile("s_waitcnt lgkmcnt(0)" ::: "memory")
#define RAWBAR() do { __builtin_amdgcn_s_barrier(); __builtin_amdgcn_sched_barrier(0); } while (0)

// ---------------- workspace layout (float offsets) ----------------
static constexpr long OFF_Q       = 0;         // 8192
static constexpr long OFF_QWB     = 8192;      // 65536 f = 131072 bf16
static constexpr long OFF_QB      = 73728;     // 128
static constexpr long OFF_PSUM    = 73856;     // 8
static constexpr long OFF_FCNT    = 73864;     // 8
static constexpr long OFF_GATES   = 73872;     // 2048
static constexpr long OFF_CTX     = 75920;     // 262144 fp32
static constexpr long OFF_ATTNOUT = 338064;    // 262144 fp32
static constexpr long OFF_EOP     = 600208;    // 8388608 fp32: 4 planes [kc][e][n][d]
static constexpr long OFF_CTXP    = 8988816;   // 1048576 fp32 (4 partials)
static constexpr long OFF_AOP     = 10037392;  // 1048576 fp32 (4 partials)
static constexpr long OFF_SCORES  = 11085968;  // 4194304 fp32 [b][ht][s]
static constexpr long OFF_AXP     = 15280272;  // 8388608 fp32: 2 planes [kc][h][b][t][d]
static constexpr long OFF_YB      = 23668880;  // 131072 f = 262144 bf16
static constexpr long OFF_HB      = 23799952;  // 4194304 f = 8388608 bf16 [e][n][hid]
// end 27994256 floats ~ 112 MB

// ---------------- q: one wave per output element ----------------
__global__ __launch_bounds__(256) void compute_q_k(const float* __restrict__ probe,
                                                   const float* __restrict__ in_w,
                                                   const float* __restrict__ in_b,
                                                   float* __restrict__ q) {
  int wid = threadIdx.x >> 6, lane = threadIdx.x & 63;
  int idx = blockIdx.x * 4 + wid;   // t*1024 + d
  int t = idx >> 10, d = idx & 1023;
  const float* pr = probe + (long)t * 1024;
  const float* wr = in_w + (long)d * 1024;
  float s = 0.f;
  for (int k = lane * 4; k < 1024; k += 256) {
    float4 a = *(const float4*)&pr[k];
    float4 b = *(const float4*)&wr[k];
    s += a.x * b.x + a.y * b.y + a.z * b.z + a.w * b.w;
  }
  for (int o = 32; o; o >>= 1) s += __shfl_xor(s, o);
  if (!lane) q[idx] = s + in_b[d];
}

// ---------------- qwb[h*8+t][d] (bf16); qb[ht] ----------------
__global__ __launch_bounds__(256) void compute_qw_k(const float* __restrict__ q,
                                                    const float* __restrict__ in_w,
                                                    const float* __restrict__ in_b,
                                                    short* __restrict__ qwb,
                                                    float* __restrict__ qb) {
  const int h = blockIdx.y;
  const int tid = threadIdx.x;
  const int d = blockIdx.x * 256 + tid;
  __shared__ float qh[8][64];
  if (tid < 64) {
#pragma unroll
    for (int t = 0; t < 8; ++t) qh[t][tid] = q[t * 1024 + h * 64 + tid] * 0.125f;
  }
  __syncthreads();
  const float* wk = in_w + 1048576 + (long)h * 64 * 1024;
  float acc[8];
#pragma unroll
  for (int t = 0; t < 8; ++t) acc[t] = 0.f;
  for (int j = 0; j < 64; ++j) {
    float w = wk[(long)j * 1024 + d];
#pragma unroll
    for (int t = 0; t < 8; ++t) acc[t] += qh[t][j] * w;
  }
#pragma unroll
  for (int t = 0; t < 8; ++t) qwb[(long)(h * 8 + t) * 1024 + d] = f2bf(acc[t]);
  if (blockIdx.x == 0 && tid < 8) {
    float s = 0.f;
    for (int j = 0; j < 64; ++j) s += qh[tid][j] * in_b[1024 + h * 64 + j];
    qb[h * 8 + tid] = s;
  }
}

// ---------------- scores: per-b, C[ht][s] = qwb @ x[b]^T (counted-vmcnt schedule) ----------------
__global__ __launch_bounds__(512)
void gemm_sc(const short* __restrict__ qwb, const float* __restrict__ xp,
             float* __restrict__ scores) {
  const int b = blockIdx.z;
  const int n0 = blockIdx.x * 64;
  const float* B = xp + (long)b * 1048576;
  float* C = scores + (long)b * 131072;
  const int tid = threadIdx.x;
  __shared__ short As[128][40], Bs[64][40];

  f32x4 acc[2][2];
#pragma unroll
  for (int i = 0; i < 2; ++i)
#pragma unroll
    for (int j = 0; j < 2; ++j)
#pragma unroll
      for (int qq = 0; qq < 4; ++qq) acc[i][j][qq] = 0.f;

  const int wid = tid >> 6, lane = tid & 63;
  const int wm = wid & 3, wn = wid >> 2;
  const int r = lane & 15, kg = (lane >> 4) * 8;
  const int am = tid >> 2, ak8 = (tid & 3) * 8;
  const int bn = tid >> 3, bk4 = (tid & 7) * 4;

  bf16x8 ra;
  float4 rb;
  auto loadT = [&](int k0) {
    ra = *(const bf16x8*)&qwb[(long)am * 1024 + k0 + ak8];
    rb = *(const float4*)&B[(long)(n0 + bn) * 1024 + k0 + bk4];
  };
  auto storeT = [&]() {
    *(bf16x8*)&As[am][ak8] = ra;
    short4v s;
    s.x = f2bf(rb.x); s.y = f2bf(rb.y); s.z = f2bf(rb.z); s.w = f2bf(rb.w);
    *(short4v*)&Bs[bn][bk4] = s;
  };
  auto compute = [&]() {
    bf16x8 af[2], bf_[2];
#pragma unroll
    for (int i = 0; i < 2; ++i) af[i] = *(const bf16x8*)&As[wm * 32 + i * 16 + r][kg];
#pragma unroll
    for (int j = 0; j < 2; ++j) bf_[j] = *(const bf16x8*)&Bs[wn * 32 + j * 16 + r][kg];
#pragma unroll
    for (int i = 0; i < 2; ++i)
#pragma unroll
      for (int j = 0; j < 2; ++j)
        acc[i][j] = __builtin_amdgcn_mfma_f32_16x16x32_bf16(af[i], bf_[j], acc[i][j], 0, 0, 0);
  };

  constexpr int NTILES = 32;
  loadT(0);
  storeT();
  loadT(32);
  LGKM0(); RAWBAR();
  for (int t = 0; t < NTILES; ++t) {
    compute();
    if (t + 1 < NTILES) {
      LGKM0(); RAWBAR();
      storeT();
      if (t + 2 < NTILES) loadT((t + 2) * 32);
      LGKM0(); RAWBAR();
    }
  }

  const int q4 = (lane >> 4) * 4;
#pragma unroll
  for (int i = 0; i < 2; ++i)
#pragma unroll
    for (int j = 0; j < 2; ++j) {
      int gn = n0 + wn * 32 + j * 16 + r;
#pragma unroll
      for (int qq = 0; qq < 4; ++qq) {
        int m = wm * 32 + i * 16 + q4 + qq;
        C[(long)m * 1024 + gn] = acc[i][j][qq];
      }
    }
}

// ---------------- split-bf16 MFMA GEMM (fp32-grade), counted-vmcnt schedule ----------------
// A: M x K fp32 (lda); APL partial planes summed (stride zA2); AKB adds kbias[k].
// B: BTRANS ? K x N row-major (swizzle-staged) : N x K row-major.
// z -> (zo=z/KS, kc=z%KS). EPI: 0 plain fp32; 4 ax scatter [h][bt][d]
template<int WM, int WN, int KS, bool AKB, bool BTRANS, int APL, int EPI>
__global__ __launch_bounds__(WM * WN * 64)
void gemm_ss(const float* __restrict__ Ap, const float* __restrict__ Bp,
             const float* __restrict__ kbias, float* __restrict__ Cp,
             int lda, int ldb, int K,
             long zA, long zA2, long zB, long zC, long ZKC, int ldc) {
  constexpr int BM = WM * 64, BN = WN * 64, BK = 32, NT = WM * WN * 64, PK = 40;
  constexpr int LA = BM * BK / (NT * 4), LB = BN * BK / (NT * 4);
  constexpr int F4 = BN / 4;
  const int z = blockIdx.z, zo = z / KS, kc = z % KS;
  const float* A = Ap + zA * zo + (long)kc * K;
  const float* B = BTRANS ? (Bp + zB * zo + (long)kc * K * ldb)
                          : (Bp + zB * zo + (long)kc * K);
  const float* kb = kbias + (long)kc * K;
  float* C = Cp + zC * zo + ZKC * kc;
  const int tid = threadIdx.x;
  const int m0 = blockIdx.y * BM, n0 = blockIdx.x * BN;
  __shared__ short Ah[BM][PK], Al[BM][PK], Bh[BN][PK], Bl[BN][PK];

  f32x4 acc[4][4];
#pragma unroll
  for (int i = 0; i < 4; ++i)
#pragma unroll
    for (int j = 0; j < 4; ++j)
#pragma unroll
      for (int qq = 0; qq < 4; ++qq) acc[i][j][qq] = 0.f;

  const int wid = tid >> 6, lane = tid & 63;
  const int wm = wid % WM, wn = wid / WM;
  const int r = lane & 15, kg = (lane >> 4) * 8;

  float4 ra[LA], rb[LB];

  auto loadT = [&](int k0) {
#pragma unroll
    for (int i = 0; i < LA; ++i) {
      int f = tid + i * NT;
      int m = f >> 3, k4 = (f & 7) * 4;
      long ofs = (long)(m0 + m) * lda + k0 + k4;
      ra[i] = *(const float4*)&A[ofs];
#pragma unroll
      for (int p = 1; p < APL; ++p) {
        float4 v2 = *(const float4*)&A[ofs + zA2 * p];
        ra[i].x += v2.x; ra[i].y += v2.y; ra[i].z += v2.z; ra[i].w += v2.w;
      }
      if (AKB) {
        float4 kv = *(const float4*)&kb[k0 + k4];
        ra[i].x += kv.x; ra[i].y += kv.y; ra[i].z += kv.z; ra[i].w += kv.w;
      }
    }
#pragma unroll
    for (int i = 0; i < LB; ++i) {
      int f = tid + i * NT;
      if (BTRANS) {
        int k = f / F4, n4 = (f % F4) * 4;
        rb[i] = *(const float4*)&B[(long)(k0 + k) * ldb + n0 + n4];
      } else {
        int n = f >> 3, k4 = (f & 7) * 4;
        rb[i] = *(const float4*)&B[(long)(n0 + n) * ldb + k0 + k4];
      }
    }
  };

  auto storeT = [&]() {
#pragma unroll
    for (int i = 0; i < LA; ++i) {
      int f = tid + i * NT;
      int m = f >> 3, k4 = (f & 7) * 4;
      short4v h, l;
      float vv[4] = {ra[i].x, ra[i].y, ra[i].z, ra[i].w};
#pragma unroll
      for (int j = 0; j < 4; ++j) {
        unsigned u = __builtin_bit_cast(unsigned, vv[j]);
        h[j] = (short)(u >> 16);
        l[j] = f2bf(vv[j] - __builtin_bit_cast(float, u & 0xFFFF0000u));
      }
      *(short4v*)&Ah[m][k4] = h;
      *(short4v*)&Al[m][k4] = l;
    }
#pragma unroll
    for (int i = 0; i < LB; ++i) {
      int f = tid + i * NT;
      float vv[4] = {rb[i].x, rb[i].y, rb[i].z, rb[i].w};
      if (BTRANS) {
        int k = f / F4, n4 = (f % F4) * 4;
        int col = bswz(k, n4);
#pragma unroll
        for (int j = 0; j < 4; ++j) {
          unsigned u = __builtin_bit_cast(unsigned, vv[j]);
          Bh[n4 + j][col] = (short)(u >> 16);
          Bl[n4 + j][col] = f2bf(vv[j] - __builtin_bit_cast(float, u & 0xFFFF0000u));
        }
      } else {
        int n = f >> 3, k4 = (f & 7) * 4;
        short4v h, l;
#pragma unroll
        for (int j = 0; j < 4; ++j) {
          unsigned u = __builtin_bit_cast(unsigned, vv[j]);
          h[j] = (short)(u >> 16);
          l[j] = f2bf(vv[j] - __builtin_bit_cast(float, u & 0xFFFF0000u));
        }
        *(short4v*)&Bh[n][k4] = h;
        *(short4v*)&Bl[n][k4] = l;
      }
    }
  };

  auto compute = [&]() {
    bf16x8 ah[4], al[4], bh[4], bl[4];
#pragma unroll
    for (int i = 0; i < 4; ++i) {
      ah[i] = *(const bf16x8*)&Ah[wm * 64 + i * 16 + r][kg];
      al[i] = *(const bf16x8*)&Al[wm * 64 + i * 16 + r][kg];
    }
#pragma unroll
    for (int j = 0; j < 4; ++j) {
      int brow = wn * 64 + j * 16 + r;
      int bcol = BTRANS ? bswz(kg, brow) : kg;
      bh[j] = *(const bf16x8*)&Bh[brow][bcol];
      bl[j] = *(const bf16x8*)&Bl[brow][bcol];
    }
#pragma unroll
    for (int i = 0; i < 4; ++i)
#pragma unroll
      for (int j = 0; j < 4; ++j) {
        acc[i][j] = __builtin_amdgcn_mfma_f32_16x16x32_bf16(ah[i], bh[j], acc[i][j], 0, 0, 0);
        acc[i][j] = __builtin_amdgcn_mfma_f32_16x16x32_bf16(ah[i], bl[j], acc[i][j], 0, 0, 0);
        acc[i][j] = __builtin_amdgcn_mfma_f32_16x16x32_bf16(al[i], bh[j], acc[i][j], 0, 0, 0);
      }
  };

  const int NTILES = K / BK;
  loadT(0);
  storeT();
  if (NTILES > 1) loadT(BK);
  LGKM0(); RAWBAR();
  for (int t = 0; t < NTILES; ++t) {
    compute();
    if (t + 1 < NTILES) {
      LGKM0(); RAWBAR();
      storeT();
      if (t + 2 < NTILES) loadT((t + 2) * BK);
      LGKM0(); RAWBAR();
    }
  }

  const int q4 = (lane >> 4) * 4;
#pragma unroll
  for (int i = 0; i < 4; ++i) {
    int gmb = m0 + wm * 64 + i * 16 + q4;
#pragma unroll
    for (int j = 0; j < 4; ++j) {
      int gn = n0 + wn * 64 + j * 16 + r;
#pragma unroll
      for (int qq = 0; qq < 4; ++qq) {
        float v = acc[i][j][qq];
        int m = gmb + qq;
        if constexpr (EPI == 0) {
          C[(long)m * ldc + gn] = v;
        } else {  // EPI == 4: m = h*8+t ; write [h][b-t-row][d]
          C[(long)(m >> 3) * 262144 + (long)(m & 7) * 1024 + gn] = v;
        }
      }
    }
  }
}

// ---------------- MoE MFMA GEMM: A bf16 MxK, B fp32 KxN (swizzled), BK=64 counted vmcnt ----------------
// 128 threads (WM=2, WN=1). EPI: 2 gelu->bf16 +bias[n]; 5 plain fp32 store (partials)
template<int KS, int EPI>
__global__ __launch_bounds__(128)
void gemm_bw(const short* __restrict__ Ap, const float* __restrict__ Bp,
             const float* __restrict__ biasp, void* __restrict__ Cp,
             int lda, int ldb, int K, long zA, long zB, long zBias, long zC, long ZKC, int ldc) {
  constexpr int BM = 128, BN = 64, BK = 64, NT = 128, PK = 72;
  constexpr int LA = BM * BK / (NT * 8);   // 8 bf16x8
  constexpr int LB = BN * BK / (NT * 4);   // 8 float4
  constexpr int F4 = BN / 4;               // 16
  const int z = blockIdx.z, zo = z / KS, kc = z % KS;
  const short* A = Ap + zA * zo + (long)kc * K;
  const float* B = Bp + zB * zo + (long)kc * K * ldb;
  const float* bias = biasp + zBias * zo;
  const int tid = threadIdx.x;
  const int m0 = blockIdx.y * BM, n0 = blockIdx.x * BN;
  __shared__ short As[BM][PK], Bs[BN][PK];

  f32x4 acc[4][4];
#pragma unroll
  for (int i = 0; i < 4; ++i)
#pragma unroll
    for (int j = 0; j < 4; ++j)
#pragma unroll
      for (int qq = 0; qq < 4; ++qq) acc[i][j][qq] = 0.f;

  const int wid = tid >> 6, lane = tid & 63;
  const int wm = wid;          // 2 waves: wm in {0,1}, wn = 0
  const int r = lane & 15, kg = (lane >> 4) * 8;

  bf16x8 ra[LA];
  float4 rb[LB];

  auto loadT = [&](int k0) {
#pragma unroll
    for (int i = 0; i < LA; ++i) {
      int f = tid + i * NT;
      int m = f >> 3, k8 = (f & 7) * 8;
      ra[i] = *(const bf16x8*)&A[(long)(m0 + m) * lda + k0 + k8];
    }
#pragma unroll
    for (int i = 0; i < LB; ++i) {
      int f = tid + i * NT;
      int k = f / F4, n4 = (f % F4) * 4;
      rb[i] = *(const float4*)&B[(long)(k0 + k) * ldb + n0 + n4];
    }
  };

  auto storeT = [&]() {
#pragma unroll
    for (int i = 0; i < LA; ++i) {
      int f = tid + i * NT;
      int m = f >> 3, k8 = (f & 7) * 8;
      *(bf16x8*)&As[m][k8] = ra[i];
    }
#pragma unroll
    for (int i = 0; i < LB; ++i) {
      int f = tid + i * NT;
      int k = f / F4, n4 = (f % F4) * 4;
      int col = bswz(k, n4);
      Bs[n4 + 0][col] = f2bf(rb[i].x);
      Bs[n4 + 1][col] = f2bf(rb[i].y);
      Bs[n4 + 2][col] = f2bf(rb[i].z);
      Bs[n4 + 3][col] = f2bf(rb[i].w);
    }
  };

  auto compute = [&]() {
#pragma unroll
    for (int kk = 0; kk < 2; ++kk) {
      bf16x8 af[4], bfr[4];
#pragma unroll
      for (int i = 0; i < 4; ++i)
        af[i] = *(const bf16x8*)&As[wm * 64 + i * 16 + r][kk * 32 + kg];
#pragma unroll
      for (int j = 0; j < 4; ++j) {
        int brow = j * 16 + r;
        bfr[j] = *(const bf16x8*)&Bs[brow][bswz(kk * 32 + kg, brow)];
      }
#pragma unroll
      for (int i = 0; i < 4; ++i)
#pragma unroll
        for (int j = 0; j < 4; ++j)
          acc[i][j] = __builtin_amdgcn_mfma_f32_16x16x32_bf16(af[i], bfr[j], acc[i][j], 0, 0, 0);
    }
  };

  const int NTILES = K / BK;
  loadT(0);
  storeT();
  if (NTILES > 1) loadT(BK);
  LGKM0(); RAWBAR();
  for (int t = 0; t < NTILES; ++t) {
    compute();
    if (t + 1 < NTILES) {
      LGKM0(); RAWBAR();
      storeT();
      if (t + 2 < NTILES) loadT((t + 2) * BK);
      LGKM0(); RAWBAR();
    }
  }

  const int q4 = (lane >> 4) * 4;
#pragma unroll
  for (int i = 0; i < 4; ++i) {
    int gmb = m0 + wm * 64 + i * 16 + q4;
#pragma unroll
    for (int j = 0; j < 4; ++j) {
      int gn = n0 + j * 16 + r;
#pragma unroll
      for (int qq = 0; qq < 4; ++qq) {
        float v = acc[i][j][qq];
        int m = gmb + qq;
        if constexpr (EPI == 2) {
          float u = v + bias[gn];
          u = 0.5f * u * (1.0f + erff(u * 0.70710678118654752f));
          ((short*)Cp + zC * zo)[(long)m * ldc + gn] = f2bf(u);
        } else {  // EPI == 5: plain fp32 partial-plane store
          ((float*)Cp + zC * zo + ZKC * kc)[(long)m * ldc + gn] = v;
        }
      }
    }
  }
}

// ---------------- reduce 4 partials ----------------
__global__ __launch_bounds__(256) void reduce4_k(const float* __restrict__ p,
                                                 float* __restrict__ out) {
  int i = (blockIdx.x * 256 + threadIdx.x) * 4;
  float4 a = *(const float4*)&p[i];
  float4 b = *(const float4*)&p[i + 262144];
  float4 c = *(const float4*)&p[i + 524288];
  float4 d = *(const float4*)&p[i + 786432];
  float4 o;
  o.x = a.x + b.x + c.x + d.x;
  o.y = a.y + b.y + c.y + d.y;
  o.z = a.z + b.z + c.z + d.z;
  o.w = a.w + b.w + c.w + d.w;
  *(float4*)&out[i] = o;
}

// ---------------- softmax over s (in place) + qb bias ----------------
__global__ __launch_bounds__(256) void softmax_k(float* __restrict__ scores,
                                                 const float* __restrict__ qb) {
  long row = blockIdx.x;            // b*128 + ht
  float bias = qb[(int)(row & 127)];
  float* p = scores + row * 1024;
  int tid = threadIdx.x;
  int wid = tid >> 6, lane = tid & 63;
  float v[4];
  float mx = -1e30f;
#pragma unroll
  for (int i = 0; i < 4; ++i) {
    v[i] = p[tid + i * 256] + bias;
    mx = fmaxf(mx, v[i]);
  }
  for (int o = 32; o; o >>= 1) mx = fmaxf(mx, __shfl_xor(mx, o));
  __shared__ float sm[4];
  __shared__ float ss[4];
  if (!lane) sm[wid] = mx;
  __syncthreads();
  mx = fmaxf(fmaxf(sm[0], sm[1]), fmaxf(sm[2], sm[3]));
  float s = 0.f;
#pragma unroll
  for (int i = 0; i < 4; ++i) { v[i] = expf(v[i] - mx); s += v[i]; }
  for (int o = 32; o; o >>= 1) s += __shfl_xor(s, o);
  if (!lane) ss[wid] = s;
  __syncthreads();
  s = ss[0] + ss[1] + ss[2] + ss[3];
  float inv = 1.0f / s;
#pragma unroll
  for (int i = 0; i < 4; ++i) p[tid + i * 256] = v[i] * inv;
}

// ---------------- attn_weights[b][t][s] = mean_h attn ----------------
__global__ __launch_bounds__(256) void attnw_k(const float* __restrict__ attn,
                                               float* __restrict__ outw) {
  int idx = blockIdx.x * 256 + threadIdx.x;
  int b = idx >> 13;
  int r = idx & 8191;
  int t = r >> 10, s = r & 1023;
  const float* p = attn + (long)b * 131072 + (long)t * 1024 + s;
  float acc = 0.f;
#pragma unroll
  for (int h = 0; h < 16; ++h) acc += p[(long)h * 8192];
  outw[idx] = acc * (1.0f / 16.0f);
}

// ---------------- fused aop-reduce + layernorm + gate softmax + top2 ----------------
__global__ __launch_bounds__(256) void ln_gate_k(const float* __restrict__ aop,
                                                 const float* __restrict__ out_b,
                                                 const float* __restrict__ gamma,
                                                 const float* __restrict__ beta,
                                                 const float* __restrict__ gate_w,
                                                 float* __restrict__ attn_out,
                                                 short* __restrict__ yb,
                                                 float* __restrict__ gates,
                                                 float* __restrict__ Psum,
                                                 float* __restrict__ fcnt) {
  int row = blockIdx.x;        // n = b*8 + t
  int t = row & 7;
  int tid = threadIdx.x;
  int wid = tid >> 6, lane = tid & 63;
  const float* xr = aop + (long)row * 1024;
  float vals[4];
  float s = 0.f, sq = 0.f;
#pragma unroll
  for (int i = 0; i < 4; ++i) {
    int d = tid + i * 256;
    float v = xr[d] + xr[d + 262144] + xr[d + 524288] + xr[d + 786432] + out_b[d];
    attn_out[(long)row * 1024 + d] = v;
    vals[i] = v;
    s += v;
    sq += v * v;
  }
  for (int o = 32; o; o >>= 1) { s += __shfl_xor(s, o); sq += __shfl_xor(sq, o); }
  __shared__ float rs[4], rss[4];
  if (!lane) { rs[wid] = s; rss[wid] = sq; }
  __syncthreads();
  s = rs[0] + rs[1] + rs[2] + rs[3];
  sq = rss[0] + rss[1] + rss[2] + rss[3];
  float mu = s * (1.0f / 1024.0f);
  float var = sq * (1.0f / 1024.0f) - mu * mu;
  float rstd = rsqrtf(var + 1e-5f);
  __shared__ float yrow[1024];
#pragma unroll
  for (int i = 0; i < 4; ++i) {
    int d = tid + i * 256;
    float yv = (vals[i] - mu) * rstd * gamma[d] + beta[d];
    yb[(long)row * 1024 + d] = f2bf(yv);
    yrow[d] = yv;
  }
  __syncthreads();
  int e = tid & 7;
  int g = tid >> 3;
  float acc = 0.f;
  const float* gw = gate_w + (long)t * 8192;
  for (int d = g; d < 1024; d += 32) acc += yrow[d] * gw[d * 8 + e];
  __shared__ float part[256];
  __shared__ float lsh[8];
  part[tid] = acc;
  __syncthreads();
  if (tid < 8) {
    float l = 0.f;
    for (int gg = 0; gg < 32; ++gg) l += part[gg * 8 + tid];
    lsh[tid] = l;
  }
  __syncthreads();
  if (tid == 0) {
    float p[8];
    float mx = -1e30f;
    for (int k = 0; k < 8; ++k) mx = fmaxf(mx, lsh[k]);
    float sum = 0.f;
    for (int k = 0; k < 8; ++k) { p[k] = expf(lsh[k] - mx); sum += p[k]; }
    float inv = 1.0f / sum;
    for (int k = 0; k < 8; ++k) p[k] *= inv;
    int i0 = 0;
    for (int k = 1; k < 8; ++k) if (p[k] > p[i0]) i0 = k;
    int i1 = -1;
    for (int k = 0; k < 8; ++k) if (k != i0 && (i1 < 0 || p[k] > p[i1])) i1 = k;
    float tot = p[i0] + p[i1];
    for (int k = 0; k < 8; ++k)
      gates[(long)row * 8 + k] = (k == i0) ? p[i0] / tot : (k == i1) ? p[i1] / tot : 0.f;
    for (int k = 0; k < 8; ++k) atomicAdd(&Psum[k], p[k]);
    atomicAdd(&fcnt[i0], 1.0f);
    atomicAdd(&fcnt[i1], 1.0f);
  }
}

// ---------------- final = attn_out(+out_b) + sum_e g_e * (sum_kc eop[kc][e] + b2[e]) ----------------
__global__ __launch_bounds__(256) void combine_k(const float* __restrict__ attn_out,
                                                 const float* __restrict__ eop,
                                                 const float* __restrict__ b2,
                                                 const float* __restrict__ gates,
                                                 float* __restrict__ outp) {
  int idx = blockIdx.x * 256 + threadIdx.x;
  int n = idx >> 10, d = idx & 1023;
  float v = attn_out[idx];
  const float* g = gates + (long)n * 8;
#pragma unroll
  for (int e = 0; e < 8; ++e) {
    float ge = g[e];
    if (ge != 0.f) {
      long base = (long)e * 262144 + idx;
      float s = eop[base] + eop[base + 2097152] + eop[base + 4194304] + eop[base + 6291456];
      v += ge * (s + b2[e * 1024 + d]);
    }
  }
  outp[idx] = v;
}

__global__ void loss_k(const float* __restrict__ Psum, const float* __restrict__ fcnt,
                       float* __restrict__ out) {
  if (threadIdx.x == 0) {
    float l = 0.f;
    for (int e = 0; e < 8; ++e) l += (fcnt[e] * (1.0f / 256.0f)) * (Psum[e] * (1.0f / 256.0f));
    out[0] = 8.0f * l;
  }
}

extern "C" void kernel_launch(void* const* d_in, const int* in_sizes, int n_in,
                              void* d_out, int out_size, void* d_ws, size_t ws_size,
                              hipStream_t stream) {
  const float* x      = (const float*)d_in[0];
  const float* probe  = (const float*)d_in[1];
  const float* in_w   = (const float*)d_in[2];
  const float* in_b   = (const float*)d_in[3];
  const float* out_w  = (const float*)d_in[4];
  const float* out_b  = (const float*)d_in[5];
  const float* gamma  = (const float*)d_in[6];
  const float* beta   = (const float*)d_in[7];
  const float* gate_w = (const float*)d_in[8];
  const float* w1     = (const float*)d_in[9];
  const float* b1     = (const float*)d_in[10];
  const float* w2     = (const float*)d_in[11];
  const float* b2     = (const float*)d_in[12];

  float* ws = (float*)d_ws;
  float* q        = ws + OFF_Q;
  short* qwb      = (short*)(ws + OFF_QWB);
  float* qb       = ws + OFF_QB;
  float* Psum     = ws + OFF_PSUM;
  float* fcnt     = ws + OFF_FCNT;
  float* gates    = ws + OFF_GATES;
  float* ctx      = ws + OFF_CTX;
  float* attn_out = ws + OFF_ATTNOUT;
  float* eop      = ws + OFF_EOP;
  float* ctxp     = ws + OFF_CTXP;
  float* aop      = ws + OFF_AOP;
  float* scores   = ws + OFF_SCORES;
  float* axp      = ws + OFF_AXP;
  short* yb       = (short*)(ws + OFF_YB);
  short* hb       = (short*)(ws + OFF_HB);

  float* out_final = (float*)d_out;
  float* out_loss  = out_final + 262144;
  float* out_attnw = out_loss + 1;

  hipMemsetAsync(ws + OFF_PSUM, 0, 16 * sizeof(float), stream);

  compute_q_k<<<2048, 256, 0, stream>>>(probe, in_w, in_b, q);
  compute_qw_k<<<dim3(4, 16, 1), 256, 0, stream>>>(q, in_w, in_b, qwb, qb);

  // scores[b][ht][s] = qwb @ x[b]^T  (per b: M=128, N=1024, K=1024)
  gemm_sc<<<dim3(16, 1, 32), 512, 0, stream>>>(qwb, x, scores);

  softmax_k<<<4096, 256, 0, stream>>>(scores, qb);
  attnw_k<<<1024, 256, 0, stream>>>(scores, out_attnw);

  // ax partials: [kc][h][b][t][d] = attn[b](:,kc*512+:) @ x[b](kc*512+:, :)  (KS=2)
  gemm_ss<2, 2, 2, false, true, 1, 4><<<dim3(8, 1, 64), 256, 0, stream>>>(
      scores, x, qb /*unused*/, axp, 1024, 1024, 512,
      131072L, 0L, 1048576L, 8192L, 4194304L, 1024);

  // ctx partials: per (h, kc): M=256, N=64, K=256 split; A = sum of 2 axp planes
  gemm_ss<1, 1, 4, false, false, 2, 0><<<dim3(1, 4, 64), 64, 0, stream>>>(
      axp, in_w + 2097152, qb /*unused*/, ctxp, 1024, 1024, 256,
      262144L, 4194304L, 65536L, 64L, 262144L, 1024);
  reduce4_k<<<256, 256, 0, stream>>>(ctxp, ctx);

  // attn_out partials: A = ctx + bv(kbias), B = out_w  (M=256, N=1024, K=256 x4) split
  gemm_ss<1, 1, 4, true, false, 1, 0><<<dim3(16, 4, 4), 64, 0, stream>>>(
      ctx, out_w, in_b + 2048, aop, 1024, 1024, 256,
      0L, 0L, 0L, 0L, 262144L, 1024);

  // fused reduce + layernorm + gate + top2 (writes attn_out with out_b folded)
  ln_gate_k<<<256, 256, 0, stream>>>(aop, out_b, gamma, beta, gate_w, attn_out,
                                     yb, gates, Psum, fcnt);

  // h[e] = gelu(yb @ w1[e] + b1[e])  (M=256, N=4096, K=1024), BK=64, 1024 blocks
  gemm_bw<1, 2><<<dim3(64, 2, 8), 128, 0, stream>>>(
      yb, w1, b1, hb, 1024, 4096, 1024, 0L, 4194304L, 4096L, 1048576L, 0L, 4096);

  // eop[kc][e] = hb(:, kc*1024+:) @ w2[e](kc*1024+:, :)  (KS=4, partial planes)
  gemm_bw<4, 5><<<dim3(16, 2, 32), 128, 0, stream>>>(
      hb, w2, b2 /*unused*/, eop, 4096, 1024, 1024, 1048576L, 4194304L, 0L, 262144L, 2097152L, 1024);

  combine_k<<<1024, 256, 0, stream>>>(attn_out, eop, b2, gates, out_final);
  loss_k<<<1, 64, 0, stream>>>(Psum, fcnt, out_loss);
}

// Round 12
// 328.479 us; speedup vs baseline: 1.1667x; 1.0741x over previous
//
#include <hip/hip_runtime.h>
#include <hip/hip_bf16.h>
#include <math.h>

// B=32, S=1024, D=1024, H=16, dh=64, T=8, E=8, HID=4096
// Outputs fp32 concat: final(262144), moe_loss(1), attn_weights(262144)

using bf16x8  = __attribute__((ext_vector_type(8))) short;
using f32x4   = __attribute__((ext_vector_type(4))) float;
using short4v = __attribute__((ext_vector_type(4))) short;

__device__ inline short f2bf(float f) {
  unsigned u = __builtin_bit_cast(unsigned, f);
  u = (u + 0x7fffu + ((u >> 16) & 1u)) >> 16;
  return (short)u;
}
__device__ inline float f4get(const float4& v, int j) {
  return j == 0 ? v.x : j == 1 ? v.y : j == 2 ? v.z : v.w;
}
// 16B-unit XOR swizzle; k in [0,64)
__device__ inline int bswz(int k, int n) {
  return (((k >> 3) ^ ((n >> 2) & 3)) << 3) | (k & 7);
}

#define LGKM0() asm volatile("s_waitcnt lgkmcnt(0)" ::: "memory")
#define RAWBAR() do { __builtin_amdgcn_s_barrier(); __builtin_amdgcn_sched_barrier(0); } while (0)

// ---------------- workspace layout (float offsets) ----------------
static constexpr long OFF_Q       = 0;         // 8192
static constexpr long OFF_QWB     = 8192;      // 65536 f = 131072 bf16
static constexpr long OFF_QB      = 73728;     // 128
static constexpr long OFF_PSUM    = 73856;     // 8
static constexpr long OFF_FCNT    = 73864;     // 8
static constexpr long OFF_GATES   = 73872;     // 2048
static constexpr long OFF_CTX     = 75920;     // 262144 fp32
static constexpr long OFF_ATTNOUT = 338064;    // 262144 fp32
static constexpr long OFF_EOP     = 600208;    // 8388608 fp32: 4 planes [kc][e][n][d]
static constexpr long OFF_CTXP    = 8988816;   // 1048576 fp32 (4 partials)
static constexpr long OFF_AOP     = 10037392;  // 1048576 fp32 (4 partials)
static constexpr long OFF_SCORES  = 11085968;  // 4194304 fp32 [b][ht][s]
static constexpr long OFF_AXP     = 15280272;  // 8388608 fp32: 2 planes [kc][h][b][t][d]
static constexpr long OFF_YB      = 23668880;  // 131072 f = 262144 bf16
static constexpr long OFF_HB      = 23799952;  // 4194304 f = 8388608 bf16 [e][n][hid]
// end 27994256 floats ~ 112 MB

// ---------------- q: one wave per output element ----------------
__global__ __launch_bounds__(256) void compute_q_k(const float* __restrict__ probe,
                                                   const float* __restrict__ in_w,
                                                   const float* __restrict__ in_b,
                                                   float* __restrict__ q) {
  int wid = threadIdx.x >> 6, lane = threadIdx.x & 63;
  int idx = blockIdx.x * 4 + wid;   // t*1024 + d
  int t = idx >> 10, d = idx & 1023;
  const float* pr = probe + (long)t * 1024;
  const float* wr = in_w + (long)d * 1024;
  float s = 0.f;
  for (int k = lane * 4; k < 1024; k += 256) {
    float4 a = *(const float4*)&pr[k];
    float4 b = *(const float4*)&wr[k];
    s += a.x * b.x + a.y * b.y + a.z * b.z + a.w * b.w;
  }
  for (int o = 32; o; o >>= 1) s += __shfl_xor(s, o);
  if (!lane) q[idx] = s + in_b[d];
}

// ---------------- qwb[h*8+t][d] (bf16); qb[ht] ----------------
__global__ __launch_bounds__(256) void compute_qw_k(const float* __restrict__ q,
                                                    const float* __restrict__ in_w,
                                                    const float* __restrict__ in_b,
                                                    short* __restrict__ qwb,
                                                    float* __restrict__ qb) {
  const int h = blockIdx.y;
  const int tid = threadIdx.x;
  const int d = blockIdx.x * 256 + tid;
  __shared__ float qh[8][64];
  if (tid < 64) {
#pragma unroll
    for (int t = 0; t < 8; ++t) qh[t][tid] = q[t * 1024 + h * 64 + tid] * 0.125f;
  }
  __syncthreads();
  const float* wk = in_w + 1048576 + (long)h * 64 * 1024;
  float acc[8];
#pragma unroll
  for (int t = 0; t < 8; ++t) acc[t] = 0.f;
  for (int j = 0; j < 64; ++j) {
    float w = wk[(long)j * 1024 + d];
#pragma unroll
    for (int t = 0; t < 8; ++t) acc[t] += qh[t][j] * w;
  }
#pragma unroll
  for (int t = 0; t < 8; ++t) qwb[(long)(h * 8 + t) * 1024 + d] = f2bf(acc[t]);
  if (blockIdx.x == 0 && tid < 8) {
    float s = 0.f;
    for (int j = 0; j < 64; ++j) s += qh[tid][j] * in_b[1024 + h * 64 + j];
    qb[h * 8 + tid] = s;
  }
}

// ---------------- scores: per-b, C[ht][s] = qwb @ x[b]^T (counted-vmcnt schedule) ----------------
__global__ __launch_bounds__(512)
void gemm_sc(const short* __restrict__ qwb, const float* __restrict__ xp,
             float* __restrict__ scores) {
  const int b = blockIdx.z;
  const int n0 = blockIdx.x * 64;
  const float* B = xp + (long)b * 1048576;
  float* C = scores + (long)b * 131072;
  const int tid = threadIdx.x;
  __shared__ short As[128][40], Bs[64][40];

  f32x4 acc[2][2];
#pragma unroll
  for (int i = 0; i < 2; ++i)
#pragma unroll
    for (int j = 0; j < 2; ++j)
#pragma unroll
      for (int qq = 0; qq < 4; ++qq) acc[i][j][qq] = 0.f;

  const int wid = tid >> 6, lane = tid & 63;
  const int wm = wid & 3, wn = wid >> 2;
  const int r = lane & 15, kg = (lane >> 4) * 8;
  const int am = tid >> 2, ak8 = (tid & 3) * 8;
  const int bn = tid >> 3, bk4 = (tid & 7) * 4;

  bf16x8 ra;
  float4 rb;
  auto loadT = [&](int k0) {
    ra = *(const bf16x8*)&qwb[(long)am * 1024 + k0 + ak8];
    rb = *(const float4*)&B[(long)(n0 + bn) * 1024 + k0 + bk4];
  };
  auto storeT = [&]() {
    *(bf16x8*)&As[am][ak8] = ra;
    short4v s;
    s.x = f2bf(rb.x); s.y = f2bf(rb.y); s.z = f2bf(rb.z); s.w = f2bf(rb.w);
    *(short4v*)&Bs[bn][bk4] = s;
  };
  auto compute = [&]() {
    bf16x8 af[2], bf_[2];
#pragma unroll
    for (int i = 0; i < 2; ++i) af[i] = *(const bf16x8*)&As[wm * 32 + i * 16 + r][kg];
#pragma unroll
    for (int j = 0; j < 2; ++j) bf_[j] = *(const bf16x8*)&Bs[wn * 32 + j * 16 + r][kg];
#pragma unroll
    for (int i = 0; i < 2; ++i)
#pragma unroll
      for (int j = 0; j < 2; ++j)
        acc[i][j] = __builtin_amdgcn_mfma_f32_16x16x32_bf16(af[i], bf_[j], acc[i][j], 0, 0, 0);
  };

  constexpr int NTILES = 32;
  loadT(0);
  storeT();
  loadT(32);
  LGKM0(); RAWBAR();
  for (int t = 0; t < NTILES; ++t) {
    compute();
    if (t + 1 < NTILES) {
      LGKM0(); RAWBAR();
      storeT();
      if (t + 2 < NTILES) loadT((t + 2) * 32);
      LGKM0(); RAWBAR();
    }
  }

  const int q4 = (lane >> 4) * 4;
#pragma unroll
  for (int i = 0; i < 2; ++i)
#pragma unroll
    for (int j = 0; j < 2; ++j) {
      int gn = n0 + wn * 32 + j * 16 + r;
#pragma unroll
      for (int qq = 0; qq < 4; ++qq) {
        int m = wm * 32 + i * 16 + q4 + qq;
        C[(long)m * 1024 + gn] = acc[i][j][qq];
      }
    }
}

// ---------------- split-bf16 MFMA GEMM (fp32-grade), counted-vmcnt schedule ----------------
// A: M x K fp32 (lda); APL partial planes summed (stride zA2); AKB adds kbias[k].
// B: BTRANS ? K x N row-major (4x4-slot swizzle-staged) : N x K row-major.
// z -> (zo=z/KS, kc=z%KS). EPI: 0 plain fp32; 4 ax scatter [h][bt][d]
template<int WM, int WN, int KS, bool AKB, bool BTRANS, int APL, int EPI>
__global__ __launch_bounds__(WM * WN * 64)
void gemm_ss(const float* __restrict__ Ap, const float* __restrict__ Bp,
             const float* __restrict__ kbias, float* __restrict__ Cp,
             int lda, int ldb, int K,
             long zA, long zA2, long zB, long zC, long ZKC, int ldc) {
  constexpr int BM = WM * 64, BN = WN * 64, BK = 32, NT = WM * WN * 64, PK = 40;
  constexpr int LA = BM * BK / (NT * 4), LB = BN * BK / (NT * 4);
  constexpr int F4 = BN / 4;
  constexpr int SLB = LB / 4;   // 4x4 slots per thread (BTRANS path)
  const int z = blockIdx.z, zo = z / KS, kc = z % KS;
  const float* A = Ap + zA * zo + (long)kc * K;
  const float* B = BTRANS ? (Bp + zB * zo + (long)kc * K * ldb)
                          : (Bp + zB * zo + (long)kc * K);
  const float* kb = kbias + (long)kc * K;
  float* C = Cp + zC * zo + ZKC * kc;
  const int tid = threadIdx.x;
  const int m0 = blockIdx.y * BM, n0 = blockIdx.x * BN;
  __shared__ short Ah[BM][PK], Al[BM][PK], Bh[BN][PK], Bl[BN][PK];

  f32x4 acc[4][4];
#pragma unroll
  for (int i = 0; i < 4; ++i)
#pragma unroll
    for (int j = 0; j < 4; ++j)
#pragma unroll
      for (int qq = 0; qq < 4; ++qq) acc[i][j][qq] = 0.f;

  const int wid = tid >> 6, lane = tid & 63;
  const int wm = wid % WM, wn = wid / WM;
  const int r = lane & 15, kg = (lane >> 4) * 8;

  float4 ra[LA], rb[LB];

  auto loadT = [&](int k0) {
#pragma unroll
    for (int i = 0; i < LA; ++i) {
      int f = tid + i * NT;
      int m = f >> 3, k4 = (f & 7) * 4;
      long ofs = (long)(m0 + m) * lda + k0 + k4;
      ra[i] = *(const float4*)&A[ofs];
#pragma unroll
      for (int p = 1; p < APL; ++p) {
        float4 v2 = *(const float4*)&A[ofs + zA2 * p];
        ra[i].x += v2.x; ra[i].y += v2.y; ra[i].z += v2.z; ra[i].w += v2.w;
      }
      if (AKB) {
        float4 kv = *(const float4*)&kb[k0 + k4];
        ra[i].x += kv.x; ra[i].y += kv.y; ra[i].z += kv.z; ra[i].w += kv.w;
      }
    }
    if (BTRANS) {
#pragma unroll
      for (int s = 0; s < SLB; ++s) {
        int slot = tid + s * NT;
        int n4 = (slot % F4) * 4, k4 = (slot / F4) * 4;
#pragma unroll
        for (int j = 0; j < 4; ++j)
          rb[s * 4 + j] = *(const float4*)&B[(long)(k0 + k4 + j) * ldb + n0 + n4];
      }
    } else {
#pragma unroll
      for (int i = 0; i < LB; ++i) {
        int f = tid + i * NT;
        int n = f >> 3, k4 = (f & 7) * 4;
        rb[i] = *(const float4*)&B[(long)(n0 + n) * ldb + k0 + k4];
      }
    }
  };

  auto storeT = [&]() {
#pragma unroll
    for (int i = 0; i < LA; ++i) {
      int f = tid + i * NT;
      int m = f >> 3, k4 = (f & 7) * 4;
      short4v h, l;
      float vv[4] = {ra[i].x, ra[i].y, ra[i].z, ra[i].w};
#pragma unroll
      for (int j = 0; j < 4; ++j) {
        unsigned u = __builtin_bit_cast(unsigned, vv[j]);
        h[j] = (short)(u >> 16);
        l[j] = f2bf(vv[j] - __builtin_bit_cast(float, u & 0xFFFF0000u));
      }
      *(short4v*)&Ah[m][k4] = h;
      *(short4v*)&Al[m][k4] = l;
    }
    if (BTRANS) {
#pragma unroll
      for (int s = 0; s < SLB; ++s) {
        int slot = tid + s * NT;
        int n4 = (slot % F4) * 4, k4 = (slot / F4) * 4;
        int col = bswz(k4, n4);
#pragma unroll
        for (int j2 = 0; j2 < 4; ++j2) {
          short4v hh, ll;
#pragma unroll
          for (int jr = 0; jr < 4; ++jr) {
            float v = f4get(rb[s * 4 + jr], j2);
            unsigned u = __builtin_bit_cast(unsigned, v);
            hh[jr] = (short)(u >> 16);
            ll[jr] = f2bf(v - __builtin_bit_cast(float, u & 0xFFFF0000u));
          }
          *(short4v*)&Bh[n4 + j2][col] = hh;
          *(short4v*)&Bl[n4 + j2][col] = ll;
        }
      }
    } else {
#pragma unroll
      for (int i = 0; i < LB; ++i) {
        int f = tid + i * NT;
        int n = f >> 3, k4 = (f & 7) * 4;
        float vv[4] = {rb[i].x, rb[i].y, rb[i].z, rb[i].w};
        short4v h, l;
#pragma unroll
        for (int j = 0; j < 4; ++j) {
          unsigned u = __builtin_bit_cast(unsigned, vv[j]);
          h[j] = (short)(u >> 16);
          l[j] = f2bf(vv[j] - __builtin_bit_cast(float, u & 0xFFFF0000u));
        }
        *(short4v*)&Bh[n][k4] = h;
        *(short4v*)&Bl[n][k4] = l;
      }
    }
  };

  auto compute = [&]() {
    bf16x8 ah[4], al[4], bh[4], bl[4];
#pragma unroll
    for (int i = 0; i < 4; ++i) {
      ah[i] = *(const bf16x8*)&Ah[wm * 64 + i * 16 + r][kg];
      al[i] = *(const bf16x8*)&Al[wm * 64 + i * 16 + r][kg];
    }
#pragma unroll
    for (int j = 0; j < 4; ++j) {
      int brow = wn * 64 + j * 16 + r;
      int bcol = BTRANS ? bswz(kg, brow) : kg;
      bh[j] = *(const bf16x8*)&Bh[brow][bcol];
      bl[j] = *(const bf16x8*)&Bl[brow][bcol];
    }
#pragma unroll
    for (int i = 0; i < 4; ++i)
#pragma unroll
      for (int j = 0; j < 4; ++j) {
        acc[i][j] = __builtin_amdgcn_mfma_f32_16x16x32_bf16(ah[i], bh[j], acc[i][j], 0, 0, 0);
        acc[i][j] = __builtin_amdgcn_mfma_f32_16x16x32_bf16(ah[i], bl[j], acc[i][j], 0, 0, 0);
        acc[i][j] = __builtin_amdgcn_mfma_f32_16x16x32_bf16(al[i], bh[j], acc[i][j], 0, 0, 0);
      }
  };

  const int NTILES = K / BK;
  loadT(0);
  storeT();
  if (NTILES > 1) loadT(BK);
  LGKM0(); RAWBAR();
  for (int t = 0; t < NTILES; ++t) {
    compute();
    if (t + 1 < NTILES) {
      LGKM0(); RAWBAR();
      storeT();
      if (t + 2 < NTILES) loadT((t + 2) * BK);
      LGKM0(); RAWBAR();
    }
  }

  const int q4 = (lane >> 4) * 4;
#pragma unroll
  for (int i = 0; i < 4; ++i) {
    int gmb = m0 + wm * 64 + i * 16 + q4;
#pragma unroll
    for (int j = 0; j < 4; ++j) {
      int gn = n0 + wn * 64 + j * 16 + r;
#pragma unroll
      for (int qq = 0; qq < 4; ++qq) {
        float v = acc[i][j][qq];
        int m = gmb + qq;
        if constexpr (EPI == 0) {
          C[(long)m * ldc + gn] = v;
        } else {  // EPI == 4: m = h*8+t ; write [h][b-t-row][d]
          C[(long)(m >> 3) * 262144 + (long)(m & 7) * 1024 + gn] = v;
        }
      }
    }
  }
}

// ---------------- MoE MFMA GEMM: A bf16 256xK, B fp32 KxN (4x4-slot swizzled), BK=64 ----------------
// 256 threads (4 waves, 64-row tiles). EPI: 2 gelu->bf16 +bias[n]; 5 fp32 partial store
template<int KS, int EPI>
__global__ __launch_bounds__(256)
void gemm_bw(const short* __restrict__ Ap, const float* __restrict__ Bp,
             const float* __restrict__ biasp, void* __restrict__ Cp,
             int lda, int ldb, int K, long zA, long zB, long zBias, long zC, long ZKC, int ldc) {
  constexpr int BM = 256, BN = 64, BK = 64, NT = 256, PK = 72;
  constexpr int LA = BM * BK / (NT * 8);   // 8 bf16x8
  constexpr int F4 = BN / 4;               // 16
  const int z = blockIdx.z, zo = z / KS, kc = z % KS;
  const short* A = Ap + zA * zo + (long)kc * K;
  const float* B = Bp + zB * zo + (long)kc * K * ldb;
  const float* bias = biasp + zBias * zo;
  const int tid = threadIdx.x;
  const int n0 = blockIdx.x * BN;
  __shared__ short As[BM][PK], Bs[BN][PK];

  f32x4 acc[4][4];
#pragma unroll
  for (int i = 0; i < 4; ++i)
#pragma unroll
    for (int j = 0; j < 4; ++j)
#pragma unroll
      for (int qq = 0; qq < 4; ++qq) acc[i][j][qq] = 0.f;

  const int wid = tid >> 6, lane = tid & 63;
  const int wm = wid;          // 4 waves: rows wm*64..+63
  const int r = lane & 15, kg = (lane >> 4) * 8;
  const int sn4 = (tid & 15) * 4, sk4 = (tid >> 4) * 4;   // B slot: 16n x 16k
  const int scol = bswz(sk4, sn4);

  bf16x8 ra[LA];
  float4 rb[4];

  auto loadT = [&](int k0) {
#pragma unroll
    for (int i = 0; i < LA; ++i) {
      int f = tid + i * NT;
      int m = f >> 3, k8 = (f & 7) * 8;
      ra[i] = *(const bf16x8*)&A[(long)m * lda + k0 + k8];
    }
#pragma unroll
    for (int j = 0; j < 4; ++j)
      rb[j] = *(const float4*)&B[(long)(k0 + sk4 + j) * ldb + n0 + sn4];
  };

  auto storeT = [&]() {
#pragma unroll
    for (int i = 0; i < LA; ++i) {
      int f = tid + i * NT;
      int m = f >> 3, k8 = (f & 7) * 8;
      *(bf16x8*)&As[m][k8] = ra[i];
    }
#pragma unroll
    for (int j2 = 0; j2 < 4; ++j2) {
      short4v s;
#pragma unroll
      for (int jr = 0; jr < 4; ++jr) s[jr] = f2bf(f4get(rb[jr], j2));
      *(short4v*)&Bs[sn4 + j2][scol] = s;
    }
  };

  auto compute = [&]() {
#pragma unroll
    for (int kk = 0; kk < 2; ++kk) {
      bf16x8 af[4], bfr[4];
#pragma unroll
      for (int i = 0; i < 4; ++i)
        af[i] = *(const bf16x8*)&As[wm * 64 + i * 16 + r][kk * 32 + kg];
#pragma unroll
      for (int j = 0; j < 4; ++j) {
        int brow = j * 16 + r;
        bfr[j] = *(const bf16x8*)&Bs[brow][bswz(kk * 32 + kg, brow)];
      }
#pragma unroll
      for (int i = 0; i < 4; ++i)
#pragma unroll
        for (int j = 0; j < 4; ++j)
          acc[i][j] = __builtin_amdgcn_mfma_f32_16x16x32_bf16(af[i], bfr[j], acc[i][j], 0, 0, 0);
    }
  };

  const int NTILES = K / BK;
  loadT(0);
  storeT();
  if (NTILES > 1) loadT(BK);
  LGKM0(); RAWBAR();
  for (int t = 0; t < NTILES; ++t) {
    compute();
    if (t + 1 < NTILES) {
      LGKM0(); RAWBAR();
      storeT();
      if (t + 2 < NTILES) loadT((t + 2) * BK);
      LGKM0(); RAWBAR();
    }
  }

  const int q4 = (lane >> 4) * 4;
#pragma unroll
  for (int i = 0; i < 4; ++i) {
    int gmb = wm * 64 + i * 16 + q4;
#pragma unroll
    for (int j = 0; j < 4; ++j) {
      int gn = n0 + j * 16 + r;
#pragma unroll
      for (int qq = 0; qq < 4; ++qq) {
        float v = acc[i][j][qq];
        int m = gmb + qq;
        if constexpr (EPI == 2) {
          float u = v + bias[gn];
          u = 0.5f * u * (1.0f + erff(u * 0.70710678118654752f));
          ((short*)Cp + zC * zo)[(long)m * ldc + gn] = f2bf(u);
        } else {  // EPI == 5: fp32 partial-plane store
          ((float*)Cp + zC * zo + ZKC * kc)[(long)m * ldc + gn] = v;
        }
      }
    }
  }
}

// ---------------- reduce 4 partials ----------------
__global__ __launch_bounds__(256) void reduce4_k(const float* __restrict__ p,
                                                 float* __restrict__ out) {
  int i = (blockIdx.x * 256 + threadIdx.x) * 4;
  float4 a = *(const float4*)&p[i];
  float4 b = *(const float4*)&p[i + 262144];
  float4 c = *(const float4*)&p[i + 524288];
  float4 d = *(const float4*)&p[i + 786432];
  float4 o;
  o.x = a.x + b.x + c.x + d.x;
  o.y = a.y + b.y + c.y + d.y;
  o.z = a.z + b.z + c.z + d.z;
  o.w = a.w + b.w + c.w + d.w;
  *(float4*)&out[i] = o;
}

// ---------------- softmax over s (in place) + qb bias ----------------
__global__ __launch_bounds__(256) void softmax_k(float* __restrict__ scores,
                                                 const float* __restrict__ qb) {
  long row = blockIdx.x;            // b*128 + ht
  float bias = qb[(int)(row & 127)];
  float* p = scores + row * 1024;
  int tid = threadIdx.x;
  int wid = tid >> 6, lane = tid & 63;
  float v[4];
  float mx = -1e30f;
#pragma unroll
  for (int i = 0; i < 4; ++i) {
    v[i] = p[tid + i * 256] + bias;
    mx = fmaxf(mx, v[i]);
  }
  for (int o = 32; o; o >>= 1) mx = fmaxf(mx, __shfl_xor(mx, o));
  __shared__ float sm[4];
  __shared__ float ss[4];
  if (!lane) sm[wid] = mx;
  __syncthreads();
  mx = fmaxf(fmaxf(sm[0], sm[1]), fmaxf(sm[2], sm[3]));
  float s = 0.f;
#pragma unroll
  for (int i = 0; i < 4; ++i) { v[i] = expf(v[i] - mx); s += v[i]; }
  for (int o = 32; o; o >>= 1) s += __shfl_xor(s, o);
  if (!lane) ss[wid] = s;
  __syncthreads();
  s = ss[0] + ss[1] + ss[2] + ss[3];
  float inv = 1.0f / s;
#pragma unroll
  for (int i = 0; i < 4; ++i) p[tid + i * 256] = v[i] * inv;
}

// ---------------- attn_weights[b][t][s] = mean_h attn ----------------
__global__ __launch_bounds__(256) void attnw_k(const float* __restrict__ attn,
                                               float* __restrict__ outw) {
  int idx = blockIdx.x * 256 + threadIdx.x;
  int b = idx >> 13;
  int r = idx & 8191;
  int t = r >> 10, s = r & 1023;
  const float* p = attn + (long)b * 131072 + (long)t * 1024 + s;
  float acc = 0.f;
#pragma unroll
  for (int h = 0; h < 16; ++h) acc += p[(long)h * 8192];
  outw[idx] = acc * (1.0f / 16.0f);
}

// ---------------- fused aop-reduce + layernorm + gate softmax + top2 ----------------
__global__ __launch_bounds__(256) void ln_gate_k(const float* __restrict__ aop,
                                                 const float* __restrict__ out_b,
                                                 const float* __restrict__ gamma,
                                                 const float* __restrict__ beta,
                                                 const float* __restrict__ gate_w,
                                                 float* __restrict__ attn_out,
                                                 short* __restrict__ yb,
                                                 float* __restrict__ gates,
                                                 float* __restrict__ Psum,
                                                 float* __restrict__ fcnt) {
  int row = blockIdx.x;        // n = b*8 + t
  int t = row & 7;
  int tid = threadIdx.x;
  int wid = tid >> 6, lane = tid & 63;
  const float* xr = aop + (long)row * 1024;
  float vals[4];
  float s = 0.f, sq = 0.f;
#pragma unroll
  for (int i = 0; i < 4; ++i) {
    int d = tid + i * 256;
    float v = xr[d] + xr[d + 262144] + xr[d + 524288] + xr[d + 786432] + out_b[d];
    attn_out[(long)row * 1024 + d] = v;
    vals[i] = v;
    s += v;
    sq += v * v;
  }
  for (int o = 32; o; o >>= 1) { s += __shfl_xor(s, o); sq += __shfl_xor(sq, o); }
  __shared__ float rs[4], rss[4];
  if (!lane) { rs[wid] = s; rss[wid] = sq; }
  __syncthreads();
  s = rs[0] + rs[1] + rs[2] + rs[3];
  sq = rss[0] + rss[1] + rss[2] + rss[3];
  float mu = s * (1.0f / 1024.0f);
  float var = sq * (1.0f / 1024.0f) - mu * mu;
  float rstd = rsqrtf(var + 1e-5f);
  __shared__ float yrow[1024];
#pragma unroll
  for (int i = 0; i < 4; ++i) {
    int d = tid + i * 256;
    float yv = (vals[i] - mu) * rstd * gamma[d] + beta[d];
    yb[(long)row * 1024 + d] = f2bf(yv);
    yrow[d] = yv;
  }
  __syncthreads();
  int e = tid & 7;
  int g = tid >> 3;
  float acc = 0.f;
  const float* gw = gate_w + (long)t * 8192;
  for (int d = g; d < 1024; d += 32) acc += yrow[d] * gw[d * 8 + e];
  __shared__ float part[256];
  __shared__ float lsh[8];
  part[tid] = acc;
  __syncthreads();
  if (tid < 8) {
    float l = 0.f;
    for (int gg = 0; gg < 32; ++gg) l += part[gg * 8 + tid];
    lsh[tid] = l;
  }
  __syncthreads();
  if (tid == 0) {
    float p[8];
    float mx = -1e30f;
    for (int k = 0; k < 8; ++k) mx = fmaxf(mx, lsh[k]);
    float sum = 0.f;
    for (int k = 0; k < 8; ++k) { p[k] = expf(lsh[k] - mx); sum += p[k]; }
    float inv = 1.0f / sum;
    for (int k = 0; k < 8; ++k) p[k] *= inv;
    int i0 = 0;
    for (int k = 1; k < 8; ++k) if (p[k] > p[i0]) i0 = k;
    int i1 = -1;
    for (int k = 0; k < 8; ++k) if (k != i0 && (i1 < 0 || p[k] > p[i1])) i1 = k;
    float tot = p[i0] + p[i1];
    for (int k = 0; k < 8; ++k)
      gates[(long)row * 8 + k] = (k == i0) ? p[i0] / tot : (k == i1) ? p[i1] / tot : 0.f;
    for (int k = 0; k < 8; ++k) atomicAdd(&Psum[k], p[k]);
    atomicAdd(&fcnt[i0], 1.0f);
    atomicAdd(&fcnt[i1], 1.0f);
  }
}

// ---------------- final = attn_out(+out_b) + sum_e g_e * (sum_kc eop[kc][e] + b2[e]) ----------------
__global__ __launch_bounds__(256) void combine_k(const float* __restrict__ attn_out,
                                                 const float* __restrict__ eop,
                                                 const float* __restrict__ b2,
                                                 const float* __restrict__ gates,
                                                 float* __restrict__ outp) {
  int idx = blockIdx.x * 256 + threadIdx.x;
  int n = idx >> 10, d = idx & 1023;
  float v = attn_out[idx];
  const float* g = gates + (long)n * 8;
#pragma unroll
  for (int e = 0; e < 8; ++e) {
    float ge = g[e];
    if (ge != 0.f) {
      long base = (long)e * 262144 + idx;
      float s = eop[base] + eop[base + 2097152] + eop[base + 4194304] + eop[base + 6291456];
      v += ge * (s + b2[e * 1024 + d]);
    }
  }
  outp[idx] = v;
}

__global__ void loss_k(const float* __restrict__ Psum, const float* __restrict__ fcnt,
                       float* __restrict__ out) {
  if (threadIdx.x == 0) {
    float l = 0.f;
    for (int e = 0; e < 8; ++e) l += (fcnt[e] * (1.0f / 256.0f)) * (Psum[e] * (1.0f / 256.0f));
    out[0] = 8.0f * l;
  }
}

extern "C" void kernel_launch(void* const* d_in, const int* in_sizes, int n_in,
                              void* d_out, int out_size, void* d_ws, size_t ws_size,
                              hipStream_t stream) {
  const float* x      = (const float*)d_in[0];
  const float* probe  = (const float*)d_in[1];
  const float* in_w   = (const float*)d_in[2];
  const float* in_b   = (const float*)d_in[3];
  const float* out_w  = (const float*)d_in[4];
  const float* out_b  = (const float*)d_in[5];
  const float* gamma  = (const float*)d_in[6];
  const float* beta   = (const float*)d_in[7];
  const float* gate_w = (const float*)d_in[8];
  const float* w1     = (const float*)d_in[9];
  const float* b1     = (const float*)d_in[10];
  const float* w2     = (const float*)d_in[11];
  const float* b2     = (const float*)d_in[12];

  float* ws = (float*)d_ws;
  float* q        = ws + OFF_Q;
  short* qwb      = (short*)(ws + OFF_QWB);
  float* qb       = ws + OFF_QB;
  float* Psum     = ws + OFF_PSUM;
  float* fcnt     = ws + OFF_FCNT;
  float* gates    = ws + OFF_GATES;
  float* ctx      = ws + OFF_CTX;
  float* attn_out = ws + OFF_ATTNOUT;
  float* eop      = ws + OFF_EOP;
  float* ctxp     = ws + OFF_CTXP;
  float* aop      = ws + OFF_AOP;
  float* scores   = ws + OFF_SCORES;
  float* axp      = ws + OFF_AXP;
  short* yb       = (short*)(ws + OFF_YB);
  short* hb       = (short*)(ws + OFF_HB);

  float* out_final = (float*)d_out;
  float* out_loss  = out_final + 262144;
  float* out_attnw = out_loss + 1;

  hipMemsetAsync(ws + OFF_PSUM, 0, 16 * sizeof(float), stream);

  compute_q_k<<<2048, 256, 0, stream>>>(probe, in_w, in_b, q);
  compute_qw_k<<<dim3(4, 16, 1), 256, 0, stream>>>(q, in_w, in_b, qwb, qb);

  // scores[b][ht][s] = qwb @ x[b]^T  (per b: M=128, N=1024, K=1024)
  gemm_sc<<<dim3(16, 1, 32), 512, 0, stream>>>(qwb, x, scores);

  softmax_k<<<4096, 256, 0, stream>>>(scores, qb);
  attnw_k<<<1024, 256, 0, stream>>>(scores, out_attnw);

  // ax partials: [kc][h][b][t][d] = attn[b](:,kc*512+:) @ x[b](kc*512+:, :)  (KS=2)
  gemm_ss<2, 2, 2, false, true, 1, 4><<<dim3(8, 1, 64), 256, 0, stream>>>(
      scores, x, qb /*unused*/, axp, 1024, 1024, 512,
      131072L, 0L, 1048576L, 8192L, 4194304L, 1024);

  // ctx partials: per (h, kc): M=256, N=64, K=256 split; A = sum of 2 axp planes
  gemm_ss<1, 1, 4, false, false, 2, 0><<<dim3(1, 4, 64), 64, 0, stream>>>(
      axp, in_w + 2097152, qb /*unused*/, ctxp, 1024, 1024, 256,
      262144L, 4194304L, 65536L, 64L, 262144L, 1024);
  reduce4_k<<<256, 256, 0, stream>>>(ctxp, ctx);

  // attn_out partials: A = ctx + bv(kbias), B = out_w  (M=256, N=1024, K=256 x4) split
  gemm_ss<1, 1, 4, true, false, 1, 0><<<dim3(16, 4, 4), 64, 0, stream>>>(
      ctx, out_w, in_b + 2048, aop, 1024, 1024, 256,
      0L, 0L, 0L, 0L, 262144L, 1024);

  // fused reduce + layernorm + gate + top2 (writes attn_out with out_b folded)
  ln_gate_k<<<256, 256, 0, stream>>>(aop, out_b, gamma, beta, gate_w, attn_out,
                                     yb, gates, Psum, fcnt);

  // h[e] = gelu(yb @ w1[e] + b1[e])  (M=256, N=4096, K=1024), BM=256, w1 read once
  gemm_bw<1, 2><<<dim3(64, 1, 8), 256, 0, stream>>>(
      yb, w1, b1, hb, 1024, 4096, 1024, 0L, 4194304L, 4096L, 1048576L, 0L, 4096);

  // eop[kc][e] = hb(:, kc*1024+:) @ w2[e](kc*1024+:, :)  (KS=4, partial planes)
  gemm_bw<4, 5><<<dim3(16, 1, 32), 256, 0, stream>>>(
      hb, w2, b2 /*unused*/, eop, 4096, 1024, 1024, 1048576L, 4194304L, 0L, 262144L, 2097152L, 1024);

  combine_k<<<1024, 256, 0, stream>>>(attn_out, eop, b2, gates, out_final);
  loss_k<<<1, 64, 0, stream>>>(Psum, fcnt, out_loss);
}